// Round 12
// baseline (182.453 us; speedup 1.0000x reference)
//
#include <hip/hip_runtime.h>

#define NFEAT 128
#define NHID  64
#define NOUT  21
#define BSH   7            // 128 nodes / bucket
#define BCAP  8192         // max edges LDS-sorted per bucket
#define CHUNK 4096         // edges per sort block (16 KB private region)
#define EPT   (CHUNK/256)  // edges per thread in k_lsort
#define PADI  16           // ints per padded counter (64 B)
#define NBUKMAX 1024       // nbuk ceiling for the packed path (N <= 2^17)

typedef unsigned int uint;
typedef unsigned short ushort_t;

typedef __bf16 bf16_t;
typedef bf16_t bf16x8 __attribute__((ext_vector_type(8)));
typedef float  f32x4  __attribute__((ext_vector_type(4)));

// bf16 pack/unpack (RTN-even)
__device__ inline uint packbf2(float a, float b) {
    uint ua = __float_as_uint(a), ub = __float_as_uint(b);
    ua = (ua + 0x7FFFu + ((ua >> 16) & 1u)) >> 16;
    ub = (ub + 0x7FFFu + ((ub >> 16) & 1u)) >> 16;
    return ua | (ub << 16);
}
__device__ inline float bflo(uint v) { return __uint_as_float(v << 16); }
__device__ inline float bfhi(uint v) { return __uint_as_float(v & 0xffff0000u); }

// ============ pass A: per-chunk LDS counting sort by bucket ============

__global__ __launch_bounds__(256) void k_lsort(const int* __restrict__ src, const int* __restrict__ dst,
                                               uint* __restrict__ ebuf, int* __restrict__ tab,
                                               int* __restrict__ gcnt, int E, int nbuk) {
    __shared__ int  lcnt[NBUKMAX + 1];
    __shared__ int  lsum[256];
    __shared__ uint lsorted[CHUNK];
    int c = blockIdx.x, tid = threadIdx.x;
    int base = c * CHUNK;
    int ccnt = min(CHUNK, E - base);

    for (int j = tid; j <= nbuk; j += 256) lcnt[j] = 0;
    __syncthreads();

    int  buk[EPT];
    uint rec[EPT];
#pragma unroll
    for (int k = 0; k < EPT; ++k) {
        int e = base + k * 256 + tid;
        if (e < E) {
            int d = dst[e];
            buk[k] = d >> BSH;
            rec[k] = ((uint)(d & ((1 << BSH) - 1)) << 17) | (uint)src[e];
            atomicAdd(&lcnt[buk[k]], 1);
        }
    }
    __syncthreads();

    int g = (nbuk + 255) / 256;
    int j0 = tid * g;
    int s = 0;
    for (int j = 0; j < g; ++j) { int idx = j0 + j; if (idx < nbuk) s += lcnt[idx]; }
    lsum[tid] = s;
    __syncthreads();
    for (int off = 1; off < 256; off <<= 1) {
        int t = (tid >= off) ? lsum[tid - off] : 0;
        __syncthreads();
        lsum[tid] += t;
        __syncthreads();
    }
    int run = lsum[tid] - s;
    for (int j = 0; j < g; ++j) {
        int idx = j0 + j;
        if (idx < nbuk) { int cv = lcnt[idx]; lcnt[idx] = run; run += cv; }
    }
    __syncthreads();
    if (tid == 0) lcnt[nbuk] = ccnt;
    __syncthreads();

    for (int j = tid; j < nbuk; j += 256) {
        int st = lcnt[j];
        tab[(size_t)c * (nbuk + 1) + j] = st;
        int cj = lcnt[j + 1] - st;
        if (cj) atomicAdd(&gcnt[j * PADI], cj);
    }
    if (tid == 0) tab[(size_t)c * (nbuk + 1) + nbuk] = ccnt;
    __syncthreads();

#pragma unroll
    for (int k = 0; k < EPT; ++k) {
        int e = base + k * 256 + tid;
        if (e < E) {
            int pos = atomicAdd(&lcnt[buk[k]], 1);
            lsorted[pos] = rec[k];
        }
    }
    __syncthreads();
    for (int i = tid; i < ccnt; i += 256) ebuf[base + i] = lsorted[i];
}

// ============ scan bucket totals -> bucket bases ============

__global__ __launch_bounds__(256) void k_bscan(const int* __restrict__ gcnt, int* __restrict__ bbase,
                                               int* __restrict__ rowptr, int nbuk, int N, int E) {
    __shared__ int lv[NBUKMAX];
    __shared__ int lsum[256];
    int tid = threadIdx.x;
    int g = (nbuk + 255) / 256;
    int j0 = tid * g;
    int s = 0;
    for (int j = 0; j < g; ++j) {
        int idx = j0 + j;
        int v = (idx < nbuk) ? gcnt[idx * PADI] : 0;
        if (idx < nbuk) lv[idx] = v;
        s += v;
    }
    lsum[tid] = s;
    __syncthreads();
    for (int off = 1; off < 256; off <<= 1) {
        int t = (tid >= off) ? lsum[tid - off] : 0;
        __syncthreads();
        lsum[tid] += t;
        __syncthreads();
    }
    int run = lsum[tid] - s;
    for (int j = 0; j < g; ++j) {
        int idx = j0 + j;
        if (idx < nbuk) { bbase[idx] = run; run += lv[idx]; }
    }
    if (tid == 0) rowptr[N] = E;
}

// ============ pass B: single-ebuf-pass bucket sort ============

__global__ __launch_bounds__(256) void k_bsort2(const uint* __restrict__ ebuf, const int* __restrict__ tab,
                                                const int* __restrict__ bbase_, const int* __restrict__ gcnt,
                                                int* __restrict__ rowptr, float* __restrict__ dinv,
                                                int* __restrict__ esrc, int nchunk, int nbuk, int N) {
    __shared__ int  ncnt[128];
    __shared__ int  sc[128];
    __shared__ int  lcur[128];
    __shared__ uint stash[BCAP];
    __shared__ int  lpos;
    int b = blockIdx.x, tid = threadIdx.x;
    int nb0 = b << BSH;
    int bb = bbase_[b];
    int cnt_b = gcnt[b * PADI];
    bool fits = (cnt_b <= BCAP);

    if (tid < 128) ncnt[tid] = 0;
    if (tid == 0) lpos = 0;
    __syncthreads();

    for (int c = tid; c < nchunk; c += 256) {
        const int* trow = tab + (size_t)c * (nbuk + 1);
        int s0 = trow[b], e0 = trow[b + 1];
        int len = e0 - s0;
        if (len <= 0) continue;
        const uint* pb = ebuf + (size_t)c * CHUNK;
        if (fits) {
            int pos = atomicAdd(&lpos, len);
            for (int i = 0; i < len; ++i) {
                uint r = pb[s0 + i];
                stash[pos + i] = r;
                atomicAdd(&ncnt[r >> 17], 1);
            }
        } else {
            for (int i = 0; i < len; ++i) atomicAdd(&ncnt[pb[s0 + i] >> 17], 1);
        }
    }
    __syncthreads();

    int v = (tid < 128) ? ncnt[tid] : 0;
    if (tid < 128) sc[tid] = v;
    __syncthreads();
    for (int off = 1; off < 128; off <<= 1) {
        int t = (tid >= off && tid < 128) ? sc[tid - off] : 0;
        __syncthreads();
        if (tid < 128) sc[tid] += t;
        __syncthreads();
    }
    if (tid < 128) {
        int excl = sc[tid] - v;
        int node = nb0 + tid;
        if (node < N) {
            rowptr[node] = bb + excl;
            dinv[node] = rsqrtf((float)(v + 1));
        }
        lcur[tid] = bb + excl;
    }
    __syncthreads();

    if (fits) {
        for (int i = tid; i < cnt_b; i += 256) {
            uint r = stash[i];
            int pos = atomicAdd(&lcur[r >> 17], 1);
            esrc[pos] = (int)(r & 0x1FFFFu);
        }
    } else {
        for (int c = tid; c < nchunk; c += 256) {
            const int* trow = tab + (size_t)c * (nbuk + 1);
            int s0 = trow[b], e0 = trow[b + 1];
            const uint* pb = ebuf + (size_t)c * CHUNK;
            for (int i = s0; i < e0; ++i) {
                uint r = pb[i];
                int pos = atomicAdd(&lcur[r >> 17], 1);
                esrc[pos] = (int)(r & 0x1FFFFu);
            }
        }
    }
}

// ============ general-N fallback (N > 2^17) ============

__global__ __launch_bounds__(256) void k_count(const int* __restrict__ dst, int* cnt, int E) {
    int e = blockIdx.x * 256 + threadIdx.x;
    if (e < E) atomicAdd(&cnt[dst[e]], 1);
}

__global__ __launch_bounds__(256) void k_scan1(const int* __restrict__ cnt, int* __restrict__ rowptr,
                                               int* __restrict__ bsum, float* __restrict__ dinv, int N) {
    __shared__ int sh[256];
    int tid = threadIdx.x;
    int base = blockIdx.x * 1024 + tid * 4;
    int v[4]; int s = 0;
#pragma unroll
    for (int j = 0; j < 4; ++j) {
        v[j] = (base + j < N) ? cnt[base + j] : 0;
        if (base + j < N) dinv[base + j] = rsqrtf((float)(v[j] + 1));
        s += v[j];
    }
    sh[tid] = s; __syncthreads();
    for (int off = 1; off < 256; off <<= 1) {
        int t = (tid >= off) ? sh[tid - off] : 0;
        __syncthreads();
        sh[tid] += t;
        __syncthreads();
    }
    int run = sh[tid] - s;
#pragma unroll
    for (int j = 0; j < 4; ++j) { if (base + j < N) rowptr[base + j] = run; run += v[j]; }
    if (tid == 255) bsum[blockIdx.x] = sh[255];
}

__global__ __launch_bounds__(128) void k_scan2(int* bsum, int nb) {
    __shared__ int sh[128];
    int tid = threadIdx.x;
    int v = (tid < nb) ? bsum[tid] : 0;
    sh[tid] = v; __syncthreads();
    for (int off = 1; off < 128; off <<= 1) {
        int t = (tid >= off) ? sh[tid - off] : 0;
        __syncthreads();
        sh[tid] += t;
        __syncthreads();
    }
    if (tid < nb) bsum[tid] = sh[tid] - v;
}

__global__ __launch_bounds__(256) void k_scan3(int* __restrict__ rowptr, int* __restrict__ fill,
                                               const int* __restrict__ bsum, int N, int E) {
    int tid = threadIdx.x;
    int base = blockIdx.x * 1024 + tid * 4;
    int add = bsum[blockIdx.x];
#pragma unroll
    for (int j = 0; j < 4; ++j) {
        int idx = base + j;
        if (idx < N) {
            int r = rowptr[idx] + add;
            rowptr[idx] = r;
            fill[idx] = r;
        }
    }
    if (blockIdx.x == 0 && tid == 0) rowptr[N] = E;
}

__global__ __launch_bounds__(256) void k_scatter_direct(const int* __restrict__ src, const int* __restrict__ dst,
                                                        int* __restrict__ fill, int* __restrict__ esrc, int E) {
    int e = blockIdx.x * 256 + threadIdx.x;
    if (e >= E) return;
    int pos = atomicAdd(&fill[dst[e]], 1);
    esrc[pos] = src[e];
}

// ===== GEMM1 via MFMA: h' = dinv * (x @ W1), bf16 in, f32 accum, bf16 out =====

__global__ __launch_bounds__(256) void k_gemm1(const float* __restrict__ x, const float* __restrict__ W1,
                                               const float* __restrict__ dinv, uint* __restrict__ hb, int N) {
    __shared__ ushort_t xs[64 * 136];   // x tile bf16 [row][k]
    __shared__ ushort_t ws[64 * 136];   // W1^T bf16 [col][k]
    int tid = threadIdx.x;
    int r0 = blockIdx.x * 64;

    {
        int col = tid & 63;
        int kb = (tid >> 6) * 32;
#pragma unroll
        for (int kk = 0; kk < 32; kk += 2) {
            float a = W1[(size_t)(kb + kk) * NHID + col];
            float b = W1[(size_t)(kb + kk + 1) * NHID + col];
            *(uint*)&ws[col * 136 + kb + kk] = packbf2(a, b);
        }
    }
    {
        int row = tid >> 2;
        int q = tid & 3;
        int grow = r0 + row;
        uint buf[16];
        if (grow < N) {
            const float* xr = x + (size_t)grow * NFEAT + q * 32;
#pragma unroll
            for (int j = 0; j < 8; ++j) {
                float4 v = *(const float4*)&xr[j * 4];
                buf[2 * j]     = packbf2(v.x, v.y);
                buf[2 * j + 1] = packbf2(v.z, v.w);
            }
        } else {
#pragma unroll
            for (int j = 0; j < 16; ++j) buf[j] = 0u;
        }
        uint* d = (uint*)&xs[row * 136 + q * 32];
#pragma unroll
        for (int j = 0; j < 4; ++j)
            ((uint4*)d)[j] = make_uint4(buf[4 * j], buf[4 * j + 1], buf[4 * j + 2], buf[4 * j + 3]);
    }
    __syncthreads();

    int lane = tid & 63;
    int wrow = (tid >> 6) * 16;
    int lrow = lane & 15;
    int lk   = (lane >> 4) * 8;

    f32x4 acc[4];
#pragma unroll
    for (int nt = 0; nt < 4; ++nt) acc[nt] = (f32x4){0.f, 0.f, 0.f, 0.f};

#pragma unroll
    for (int kq = 0; kq < 4; ++kq) {
        int k0 = kq * 32;
        bf16x8 a = *(const bf16x8*)&xs[(wrow + lrow) * 136 + k0 + lk];
#pragma unroll
        for (int nt = 0; nt < 4; ++nt) {
            bf16x8 b = *(const bf16x8*)&ws[(nt * 16 + lrow) * 136 + k0 + lk];
            acc[nt] = __builtin_amdgcn_mfma_f32_16x16x32_bf16(a, b, acc[nt], 0, 0, 0);
        }
    }

    int orow0 = (lane >> 4) * 4;
    float dvv[4];
#pragma unroll
    for (int r = 0; r < 4; ++r) {
        int grow = r0 + wrow + orow0 + r;
        dvv[r] = (grow < N) ? dinv[grow] : 0.f;
    }
    ushort_t* hbs = (ushort_t*)hb;
#pragma unroll
    for (int nt = 0; nt < 4; ++nt) {
#pragma unroll
        for (int r = 0; r < 4; ++r) {
            int grow = r0 + wrow + orow0 + r;
            if (grow < N) {
                uint pb = packbf2(acc[nt][r] * dvv[r], 0.f);
                hbs[(size_t)grow * 64 + nt * 16 + lrow] = (ushort_t)(pb & 0xffffu);
            }
        }
    }
}

// ===== agg1f: o1 = relu(b1 + dv*(h'[d] + sum_e h'[src_e])) kept in LDS,
//       then h2' = dinv * (o1 @ W2) computed in-wave, bf16 h2b row stored. =====

__global__ __launch_bounds__(256) void k_agg1f(const int* __restrict__ rowptr, const int* __restrict__ esrc,
                                               const uint* __restrict__ hb, const float* __restrict__ dinv,
                                               const float* __restrict__ b1, const float* __restrict__ W2,
                                               uint* __restrict__ h2b, int N) {
    __shared__ float W2s[NHID * NOUT];  // 5.25 KB
    __shared__ float o1s[4][NHID];      // 1 KB, per-wave row buffer
    int tid = threadIdx.x;
    for (int i = tid; i < NHID * NOUT; i += 256) W2s[i] = W2[i];
    __syncthreads();

    int wid = tid >> 6;
    int node = blockIdx.x * 4 + wid;
    if (node >= N) return;
    int lane = tid & 63;
    int half = lane >> 5;
    int c = lane & 31;
    uint sv = hb[(size_t)node * 32 + c];
    float ax = half ? 0.f : bflo(sv);
    float ay = half ? 0.f : bfhi(sv);
    int beg = rowptr[node], end = rowptr[node + 1];
    int i = beg + half;
    for (; i + 14 < end; i += 16) {
        int s0 = esrc[i], s1 = esrc[i + 2], s2 = esrc[i + 4], s3 = esrc[i + 6];
        int s4 = esrc[i + 8], s5 = esrc[i + 10], s6 = esrc[i + 12], s7 = esrc[i + 14];
        uint v0 = hb[(size_t)s0 * 32 + c];
        uint v1 = hb[(size_t)s1 * 32 + c];
        uint v2 = hb[(size_t)s2 * 32 + c];
        uint v3 = hb[(size_t)s3 * 32 + c];
        uint v4 = hb[(size_t)s4 * 32 + c];
        uint v5 = hb[(size_t)s5 * 32 + c];
        uint v6 = hb[(size_t)s6 * 32 + c];
        uint v7 = hb[(size_t)s7 * 32 + c];
        ax += bflo(v0) + bflo(v1);
        ay += bfhi(v0) + bfhi(v1);
        ax += bflo(v2) + bflo(v3);
        ay += bfhi(v2) + bfhi(v3);
        ax += bflo(v4) + bflo(v5);
        ay += bfhi(v4) + bfhi(v5);
        ax += bflo(v6) + bflo(v7);
        ay += bfhi(v6) + bfhi(v7);
    }
    for (; i + 6 < end; i += 8) {
        int s0 = esrc[i], s1 = esrc[i + 2], s2 = esrc[i + 4], s3 = esrc[i + 6];
        uint v0 = hb[(size_t)s0 * 32 + c];
        uint v1 = hb[(size_t)s1 * 32 + c];
        uint v2 = hb[(size_t)s2 * 32 + c];
        uint v3 = hb[(size_t)s3 * 32 + c];
        ax += bflo(v0) + bflo(v1);
        ay += bfhi(v0) + bfhi(v1);
        ax += bflo(v2) + bflo(v3);
        ay += bfhi(v2) + bfhi(v3);
    }
    for (; i < end; i += 2) {
        uint v = hb[(size_t)esrc[i] * 32 + c];
        ax += bflo(v); ay += bfhi(v);
    }
    ax += __shfl_xor(ax, 32);
    ay += __shfl_xor(ay, 32);
    float dv = dinv[node];
    if (!half) {
        float2 bv = ((const float2*)b1)[c];
        float2 r;
        r.x = fmaxf(fmaf(ax, dv, bv.x), 0.f);
        r.y = fmaxf(fmaf(ay, dv, bv.y), 0.f);
        *(float2*)&o1s[wid][2 * c] = r;                // feats 2c, 2c+1
    }
    __threadfence_block();                             // LDS write -> read, intra-wave

    // h2[j] = dv * sum_k o1[k] * W2[k][j], lanes 0..20
    float h2v = 0.f;
    if (lane < NOUT) {
        const float* orow = o1s[wid];
        float accj = 0.f;
#pragma unroll 8
        for (int k = 0; k < NHID; ++k) accj = fmaf(orow[k], W2s[k * NOUT + lane], accj);
        h2v = accj * dv;
    }
    // pack pairs via shfl; lanes >= NOUT hold 0 so padding packs to 0
    float lo = __shfl(h2v, 2 * (lane & 15));
    float hi = __shfl(h2v, 2 * (lane & 15) + 1);
    if (lane < 16) h2b[(size_t)node * 16 + lane] = packbf2(lo, hi);
}

// ===== agg2: out[d] = b2 + dv_d*(h2'[d] + sum_e h2'[src_e]) =====

__global__ __launch_bounds__(256) void k_agg2(const int* __restrict__ rowptr, const int* __restrict__ esrc,
                                              const uint* __restrict__ h2b, const float* __restrict__ dinv,
                                              const float* __restrict__ b2, float* __restrict__ out, int N) {
    int tid = threadIdx.x;
    int node = blockIdx.x * 64 + (tid >> 2);
    if (node >= N) return;
    int q = tid & 3;
    uint4 sv = *((const uint4*)(h2b + (size_t)node * 16) + q);
    float a0 = bflo(sv.x), a1 = bfhi(sv.x), a2 = bflo(sv.y), a3 = bfhi(sv.y);
    float a4 = bflo(sv.z), a5 = bfhi(sv.z), a6 = bflo(sv.w), a7 = bfhi(sv.w);
    int beg = rowptr[node], end = rowptr[node + 1];
    int i = beg;
    for (; i + 3 < end; i += 4) {
        int s0 = esrc[i], s1 = esrc[i + 1], s2 = esrc[i + 2], s3 = esrc[i + 3];
        uint4 v0 = *((const uint4*)(h2b + (size_t)s0 * 16) + q);
        uint4 v1 = *((const uint4*)(h2b + (size_t)s1 * 16) + q);
        uint4 v2 = *((const uint4*)(h2b + (size_t)s2 * 16) + q);
        uint4 v3 = *((const uint4*)(h2b + (size_t)s3 * 16) + q);
        a0 += bflo(v0.x) + bflo(v1.x);
        a1 += bfhi(v0.x) + bfhi(v1.x);
        a2 += bflo(v0.y) + bflo(v1.y);
        a3 += bfhi(v0.y) + bfhi(v1.y);
        a4 += bflo(v0.z) + bflo(v1.z);
        a5 += bfhi(v0.z) + bfhi(v1.z);
        a6 += bflo(v0.w) + bflo(v1.w);
        a7 += bfhi(v0.w) + bfhi(v1.w);
        a0 += bflo(v2.x) + bflo(v3.x);
        a1 += bfhi(v2.x) + bfhi(v3.x);
        a2 += bflo(v2.y) + bflo(v3.y);
        a3 += bfhi(v2.y) + bfhi(v3.y);
        a4 += bflo(v2.z) + bflo(v3.z);
        a5 += bfhi(v2.z) + bfhi(v3.z);
        a6 += bflo(v2.w) + bflo(v3.w);
        a7 += bfhi(v2.w) + bfhi(v3.w);
    }
    for (; i < end; ++i) {
        uint4 v0 = *((const uint4*)(h2b + (size_t)esrc[i] * 16) + q);
        a0 += bflo(v0.x); a1 += bfhi(v0.x);
        a2 += bflo(v0.y); a3 += bfhi(v0.y);
        a4 += bflo(v0.z); a5 += bfhi(v0.z);
        a6 += bflo(v0.w); a7 += bfhi(v0.w);
    }
    float dv = dinv[node];
    float* orow = out + (size_t)node * NOUT;
    int col = q * 8;
    float av[8] = {a0, a1, a2, a3, a4, a5, a6, a7};
#pragma unroll
    for (int j = 0; j < 8; ++j)
        if (col + j < NOUT) orow[col + j] = fmaf(dv, av[j], b2[col + j]);
}

// ================= launch =================

extern "C" void kernel_launch(void* const* d_in, const int* in_sizes, int n_in,
                              void* d_out, int out_size, void* d_ws, size_t ws_size,
                              hipStream_t stream) {
    const float* x  = (const float*)d_in[0];
    const int*   ei = (const int*)d_in[1];
    const float* W1 = (const float*)d_in[2];
    const float* b1 = (const float*)d_in[3];
    const float* W2 = (const float*)d_in[4];
    const float* b2 = (const float*)d_in[5];
    float* out = (float*)d_out;

    int N = in_sizes[0] / NFEAT;
    int E = in_sizes[1] / 2;
    const int* src = ei;
    const int* dst = ei + E;
    int NBUK = (N + (1 << BSH) - 1) >> BSH;
    int NCHUNK = (E + CHUNK - 1) / CHUNK;

    char* p = (char*)d_ws;
    auto alloc = [&](size_t bytes) { void* r = (void*)p; p += (bytes + 255) & ~(size_t)255; return r; };
    int*   rowptr = (int*)alloc((size_t)(N + 1) * 4);
    int*   gcnt   = (int*)alloc((size_t)NBUK * PADI * 4);
    int*   bbase  = (int*)alloc((size_t)NBUK * 4);
    int*   tab    = (int*)alloc((size_t)NCHUNK * (NBUK + 1) * 4);
    uint*  ebuf   = (uint*)alloc((size_t)E * 4);
    int*   esrc   = (int*)alloc((size_t)E * 4);
    float* dinv   = (float*)alloc((size_t)N * 4);
    uint*  hb     = (uint*)alloc((size_t)N * 32 * 4);
    uint*  h2b    = (uint*)alloc((size_t)N * 16 * 4);   // bf16 rows padded to 64 B
    int*   cnt    = (int*)alloc((size_t)N * 4);      // fallback only
    int*   fill   = (int*)alloc((size_t)N * 4);      // fallback only
    int*   bsum   = (int*)alloc(128 * 4);            // fallback only

    const int B = 256;

    if (N <= (1 << 17)) {
        hipMemsetAsync(gcnt, 0, (size_t)NBUK * PADI * 4, stream);
        k_lsort <<<NCHUNK, 256, 0, stream>>>(src, dst, ebuf, tab, gcnt, E, NBUK);
        k_bscan <<<1, 256, 0, stream>>>(gcnt, bbase, rowptr, NBUK, N, E);
        k_bsort2<<<NBUK, 256, 0, stream>>>(ebuf, tab, bbase, gcnt, rowptr, dinv, esrc, NCHUNK, NBUK, N);
    } else {
        int nb = (N + 1023) / 1024;
        hipMemsetAsync(cnt, 0, (size_t)N * 4, stream);
        k_count <<<(E + B - 1) / B, B, 0, stream>>>(dst, cnt, E);
        k_scan1 <<<nb, 256, 0, stream>>>(cnt, rowptr, bsum, dinv, N);
        k_scan2 <<<1, 128, 0, stream>>>(bsum, nb);
        k_scan3 <<<nb, 256, 0, stream>>>(rowptr, fill, bsum, N, E);
        k_scatter_direct<<<(E + B - 1) / B, B, 0, stream>>>(src, dst, fill, esrc, E);
    }

    k_gemm1 <<<(N + 63) / 64, 256, 0, stream>>>(x, W1, dinv, hb, N);
    k_agg1f <<<(N + 3) / 4, 256, 0, stream>>>(rowptr, esrc, hb, dinv, b1, W2, h2b, N);
    k_agg2  <<<(N + 63) / 64, 256, 0, stream>>>(rowptr, esrc, h2b, dinv, b2, out, N);
}

// Round 13
// 164.514 us; speedup vs baseline: 1.1090x; 1.1090x over previous
//
#include <hip/hip_runtime.h>

#define NFEAT 128
#define NHID  64
#define NOUT  21
#define BSH   7            // 128 nodes / bucket
#define BCAP  8192         // max edges LDS-sorted per bucket
#define CHUNK 4096         // edges per sort block (16 KB private region)
#define EPT   (CHUNK/256)  // edges per thread in k_lsort
#define PADI  16           // ints per padded counter (64 B)
#define NBUKMAX 1024       // nbuk ceiling for the packed path (N <= 2^17)

typedef unsigned int uint;
typedef unsigned short ushort_t;

typedef __bf16 bf16_t;
typedef bf16_t bf16x8 __attribute__((ext_vector_type(8)));
typedef float  f32x4  __attribute__((ext_vector_type(4)));

// bf16 pack/unpack (RTN-even)
__device__ inline uint packbf2(float a, float b) {
    uint ua = __float_as_uint(a), ub = __float_as_uint(b);
    ua = (ua + 0x7FFFu + ((ua >> 16) & 1u)) >> 16;
    ub = (ub + 0x7FFFu + ((ub >> 16) & 1u)) >> 16;
    return ua | (ub << 16);
}
__device__ inline float bflo(uint v) { return __uint_as_float(v << 16); }
__device__ inline float bfhi(uint v) { return __uint_as_float(v & 0xffff0000u); }

// ============ pass A: per-chunk LDS counting sort by bucket ============

__global__ __launch_bounds__(256) void k_lsort(const int* __restrict__ src, const int* __restrict__ dst,
                                               uint* __restrict__ ebuf, int* __restrict__ tab,
                                               int* __restrict__ gcnt, int E, int nbuk) {
    __shared__ int  lcnt[NBUKMAX + 1];
    __shared__ int  lsum[256];
    __shared__ uint lsorted[CHUNK];
    int c = blockIdx.x, tid = threadIdx.x;
    int base = c * CHUNK;
    int ccnt = min(CHUNK, E - base);

    for (int j = tid; j <= nbuk; j += 256) lcnt[j] = 0;
    __syncthreads();

    int  buk[EPT];
    uint rec[EPT];
#pragma unroll
    for (int k = 0; k < EPT; ++k) {
        int e = base + k * 256 + tid;
        if (e < E) {
            int d = dst[e];
            buk[k] = d >> BSH;
            rec[k] = ((uint)(d & ((1 << BSH) - 1)) << 17) | (uint)src[e];
            atomicAdd(&lcnt[buk[k]], 1);
        }
    }
    __syncthreads();

    int g = (nbuk + 255) / 256;
    int j0 = tid * g;
    int s = 0;
    for (int j = 0; j < g; ++j) { int idx = j0 + j; if (idx < nbuk) s += lcnt[idx]; }
    lsum[tid] = s;
    __syncthreads();
    for (int off = 1; off < 256; off <<= 1) {
        int t = (tid >= off) ? lsum[tid - off] : 0;
        __syncthreads();
        lsum[tid] += t;
        __syncthreads();
    }
    int run = lsum[tid] - s;
    for (int j = 0; j < g; ++j) {
        int idx = j0 + j;
        if (idx < nbuk) { int cv = lcnt[idx]; lcnt[idx] = run; run += cv; }
    }
    __syncthreads();
    if (tid == 0) lcnt[nbuk] = ccnt;
    __syncthreads();

    for (int j = tid; j < nbuk; j += 256) {
        int st = lcnt[j];
        tab[(size_t)c * (nbuk + 1) + j] = st;
        int cj = lcnt[j + 1] - st;
        if (cj) atomicAdd(&gcnt[j * PADI], cj);
    }
    if (tid == 0) tab[(size_t)c * (nbuk + 1) + nbuk] = ccnt;
    __syncthreads();

#pragma unroll
    for (int k = 0; k < EPT; ++k) {
        int e = base + k * 256 + tid;
        if (e < E) {
            int pos = atomicAdd(&lcnt[buk[k]], 1);
            lsorted[pos] = rec[k];
        }
    }
    __syncthreads();
    for (int i = tid; i < ccnt; i += 256) ebuf[base + i] = lsorted[i];
}

// ============ scan bucket totals -> bucket bases ============

__global__ __launch_bounds__(256) void k_bscan(const int* __restrict__ gcnt, int* __restrict__ bbase,
                                               int* __restrict__ rowptr, int nbuk, int N, int E) {
    __shared__ int lv[NBUKMAX];
    __shared__ int lsum[256];
    int tid = threadIdx.x;
    int g = (nbuk + 255) / 256;
    int j0 = tid * g;
    int s = 0;
    for (int j = 0; j < g; ++j) {
        int idx = j0 + j;
        int v = (idx < nbuk) ? gcnt[idx * PADI] : 0;
        if (idx < nbuk) lv[idx] = v;
        s += v;
    }
    lsum[tid] = s;
    __syncthreads();
    for (int off = 1; off < 256; off <<= 1) {
        int t = (tid >= off) ? lsum[tid - off] : 0;
        __syncthreads();
        lsum[tid] += t;
        __syncthreads();
    }
    int run = lsum[tid] - s;
    for (int j = 0; j < g; ++j) {
        int idx = j0 + j;
        if (idx < nbuk) { bbase[idx] = run; run += lv[idx]; }
    }
    if (tid == 0) rowptr[N] = E;
}

// ============ pass B: single-ebuf-pass bucket sort ============

__global__ __launch_bounds__(256) void k_bsort2(const uint* __restrict__ ebuf, const int* __restrict__ tab,
                                                const int* __restrict__ bbase_, const int* __restrict__ gcnt,
                                                int* __restrict__ rowptr, float* __restrict__ dinv,
                                                int* __restrict__ esrc, int nchunk, int nbuk, int N) {
    __shared__ int  ncnt[128];
    __shared__ int  sc[128];
    __shared__ int  lcur[128];
    __shared__ uint stash[BCAP];
    __shared__ int  lpos;
    int b = blockIdx.x, tid = threadIdx.x;
    int nb0 = b << BSH;
    int bb = bbase_[b];
    int cnt_b = gcnt[b * PADI];
    bool fits = (cnt_b <= BCAP);

    if (tid < 128) ncnt[tid] = 0;
    if (tid == 0) lpos = 0;
    __syncthreads();

    for (int c = tid; c < nchunk; c += 256) {
        const int* trow = tab + (size_t)c * (nbuk + 1);
        int s0 = trow[b], e0 = trow[b + 1];
        int len = e0 - s0;
        if (len <= 0) continue;
        const uint* pb = ebuf + (size_t)c * CHUNK;
        if (fits) {
            int pos = atomicAdd(&lpos, len);
            for (int i = 0; i < len; ++i) {
                uint r = pb[s0 + i];
                stash[pos + i] = r;
                atomicAdd(&ncnt[r >> 17], 1);
            }
        } else {
            for (int i = 0; i < len; ++i) atomicAdd(&ncnt[pb[s0 + i] >> 17], 1);
        }
    }
    __syncthreads();

    int v = (tid < 128) ? ncnt[tid] : 0;
    if (tid < 128) sc[tid] = v;
    __syncthreads();
    for (int off = 1; off < 128; off <<= 1) {
        int t = (tid >= off && tid < 128) ? sc[tid - off] : 0;
        __syncthreads();
        if (tid < 128) sc[tid] += t;
        __syncthreads();
    }
    if (tid < 128) {
        int excl = sc[tid] - v;
        int node = nb0 + tid;
        if (node < N) {
            rowptr[node] = bb + excl;
            dinv[node] = rsqrtf((float)(v + 1));
        }
        lcur[tid] = bb + excl;
    }
    __syncthreads();

    if (fits) {
        for (int i = tid; i < cnt_b; i += 256) {
            uint r = stash[i];
            int pos = atomicAdd(&lcur[r >> 17], 1);
            esrc[pos] = (int)(r & 0x1FFFFu);
        }
    } else {
        for (int c = tid; c < nchunk; c += 256) {
            const int* trow = tab + (size_t)c * (nbuk + 1);
            int s0 = trow[b], e0 = trow[b + 1];
            const uint* pb = ebuf + (size_t)c * CHUNK;
            for (int i = s0; i < e0; ++i) {
                uint r = pb[i];
                int pos = atomicAdd(&lcur[r >> 17], 1);
                esrc[pos] = (int)(r & 0x1FFFFu);
            }
        }
    }
}

// ============ general-N fallback (N > 2^17) ============

__global__ __launch_bounds__(256) void k_count(const int* __restrict__ dst, int* cnt, int E) {
    int e = blockIdx.x * 256 + threadIdx.x;
    if (e < E) atomicAdd(&cnt[dst[e]], 1);
}

__global__ __launch_bounds__(256) void k_scan1(const int* __restrict__ cnt, int* __restrict__ rowptr,
                                               int* __restrict__ bsum, float* __restrict__ dinv, int N) {
    __shared__ int sh[256];
    int tid = threadIdx.x;
    int base = blockIdx.x * 1024 + tid * 4;
    int v[4]; int s = 0;
#pragma unroll
    for (int j = 0; j < 4; ++j) {
        v[j] = (base + j < N) ? cnt[base + j] : 0;
        if (base + j < N) dinv[base + j] = rsqrtf((float)(v[j] + 1));
        s += v[j];
    }
    sh[tid] = s; __syncthreads();
    for (int off = 1; off < 256; off <<= 1) {
        int t = (tid >= off) ? sh[tid - off] : 0;
        __syncthreads();
        sh[tid] += t;
        __syncthreads();
    }
    int run = sh[tid] - s;
#pragma unroll
    for (int j = 0; j < 4; ++j) { if (base + j < N) rowptr[base + j] = run; run += v[j]; }
    if (tid == 255) bsum[blockIdx.x] = sh[255];
}

__global__ __launch_bounds__(128) void k_scan2(int* bsum, int nb) {
    __shared__ int sh[128];
    int tid = threadIdx.x;
    int v = (tid < nb) ? bsum[tid] : 0;
    sh[tid] = v; __syncthreads();
    for (int off = 1; off < 128; off <<= 1) {
        int t = (tid >= off) ? sh[tid - off] : 0;
        __syncthreads();
        sh[tid] += t;
        __syncthreads();
    }
    if (tid < nb) bsum[tid] = sh[tid] - v;
}

__global__ __launch_bounds__(256) void k_scan3(int* __restrict__ rowptr, int* __restrict__ fill,
                                               const int* __restrict__ bsum, int N, int E) {
    int tid = threadIdx.x;
    int base = blockIdx.x * 1024 + tid * 4;
    int add = bsum[blockIdx.x];
#pragma unroll
    for (int j = 0; j < 4; ++j) {
        int idx = base + j;
        if (idx < N) {
            int r = rowptr[idx] + add;
            rowptr[idx] = r;
            fill[idx] = r;
        }
    }
    if (blockIdx.x == 0 && tid == 0) rowptr[N] = E;
}

__global__ __launch_bounds__(256) void k_scatter_direct(const int* __restrict__ src, const int* __restrict__ dst,
                                                        int* __restrict__ fill, int* __restrict__ esrc, int E) {
    int e = blockIdx.x * 256 + threadIdx.x;
    if (e >= E) return;
    int pos = atomicAdd(&fill[dst[e]], 1);
    esrc[pos] = src[e];
}

// ===== GEMM1 via MFMA: h' = dinv * (x @ W1), bf16 in, f32 accum, bf16 out =====

__global__ __launch_bounds__(256) void k_gemm1(const float* __restrict__ x, const float* __restrict__ W1,
                                               const float* __restrict__ dinv, uint* __restrict__ hb, int N) {
    __shared__ ushort_t xs[64 * 136];   // x tile bf16 [row][k]
    __shared__ ushort_t ws[64 * 136];   // W1^T bf16 [col][k]
    int tid = threadIdx.x;
    int r0 = blockIdx.x * 64;

    {
        int col = tid & 63;
        int kb = (tid >> 6) * 32;
#pragma unroll
        for (int kk = 0; kk < 32; kk += 2) {
            float a = W1[(size_t)(kb + kk) * NHID + col];
            float b = W1[(size_t)(kb + kk + 1) * NHID + col];
            *(uint*)&ws[col * 136 + kb + kk] = packbf2(a, b);
        }
    }
    {
        int row = tid >> 2;
        int q = tid & 3;
        int grow = r0 + row;
        uint buf[16];
        if (grow < N) {
            const float* xr = x + (size_t)grow * NFEAT + q * 32;
#pragma unroll
            for (int j = 0; j < 8; ++j) {
                float4 v = *(const float4*)&xr[j * 4];
                buf[2 * j]     = packbf2(v.x, v.y);
                buf[2 * j + 1] = packbf2(v.z, v.w);
            }
        } else {
#pragma unroll
            for (int j = 0; j < 16; ++j) buf[j] = 0u;
        }
        uint* d = (uint*)&xs[row * 136 + q * 32];
#pragma unroll
        for (int j = 0; j < 4; ++j)
            ((uint4*)d)[j] = make_uint4(buf[4 * j], buf[4 * j + 1], buf[4 * j + 2], buf[4 * j + 3]);
    }
    __syncthreads();

    int lane = tid & 63;
    int wrow = (tid >> 6) * 16;
    int lrow = lane & 15;
    int lk   = (lane >> 4) * 8;

    f32x4 acc[4];
#pragma unroll
    for (int nt = 0; nt < 4; ++nt) acc[nt] = (f32x4){0.f, 0.f, 0.f, 0.f};

#pragma unroll
    for (int kq = 0; kq < 4; ++kq) {
        int k0 = kq * 32;
        bf16x8 a = *(const bf16x8*)&xs[(wrow + lrow) * 136 + k0 + lk];
#pragma unroll
        for (int nt = 0; nt < 4; ++nt) {
            bf16x8 b = *(const bf16x8*)&ws[(nt * 16 + lrow) * 136 + k0 + lk];
            acc[nt] = __builtin_amdgcn_mfma_f32_16x16x32_bf16(a, b, acc[nt], 0, 0, 0);
        }
    }

    int orow0 = (lane >> 4) * 4;
    float dvv[4];
#pragma unroll
    for (int r = 0; r < 4; ++r) {
        int grow = r0 + wrow + orow0 + r;
        dvv[r] = (grow < N) ? dinv[grow] : 0.f;
    }
    ushort_t* hbs = (ushort_t*)hb;
#pragma unroll
    for (int nt = 0; nt < 4; ++nt) {
#pragma unroll
        for (int r = 0; r < 4; ++r) {
            int grow = r0 + wrow + orow0 + r;
            if (grow < N) {
                uint pb = packbf2(acc[nt][r] * dvv[r], 0.f);
                hbs[(size_t)grow * 64 + nt * 16 + lrow] = (ushort_t)(pb & 0xffffu);
            }
        }
    }
}

// ===== agg1: o1 = relu(b1 + dv*(h'[d] + sum_e h'[src_e])), packed bf16 out =====

__global__ __launch_bounds__(256) void k_agg1(const int* __restrict__ rowptr, const int* __restrict__ esrc,
                                              const uint* __restrict__ hb, const float* __restrict__ dinv,
                                              const float* __restrict__ b1, uint* __restrict__ o1b, int N) {
    int tid = threadIdx.x;
    int node = blockIdx.x * 4 + (tid >> 6);
    if (node >= N) return;
    int lane = tid & 63;
    int half = lane >> 5;
    int c = lane & 31;
    uint sv = hb[(size_t)node * 32 + c];
    float ax = half ? 0.f : bflo(sv);
    float ay = half ? 0.f : bfhi(sv);
    int beg = rowptr[node], end = rowptr[node + 1];
    int i = beg + half;
    for (; i + 14 < end; i += 16) {
        int s0 = esrc[i], s1 = esrc[i + 2], s2 = esrc[i + 4], s3 = esrc[i + 6];
        int s4 = esrc[i + 8], s5 = esrc[i + 10], s6 = esrc[i + 12], s7 = esrc[i + 14];
        uint v0 = hb[(size_t)s0 * 32 + c];
        uint v1 = hb[(size_t)s1 * 32 + c];
        uint v2 = hb[(size_t)s2 * 32 + c];
        uint v3 = hb[(size_t)s3 * 32 + c];
        uint v4 = hb[(size_t)s4 * 32 + c];
        uint v5 = hb[(size_t)s5 * 32 + c];
        uint v6 = hb[(size_t)s6 * 32 + c];
        uint v7 = hb[(size_t)s7 * 32 + c];
        ax += bflo(v0) + bflo(v1);
        ay += bfhi(v0) + bfhi(v1);
        ax += bflo(v2) + bflo(v3);
        ay += bfhi(v2) + bfhi(v3);
        ax += bflo(v4) + bflo(v5);
        ay += bfhi(v4) + bfhi(v5);
        ax += bflo(v6) + bflo(v7);
        ay += bfhi(v6) + bfhi(v7);
    }
    for (; i + 6 < end; i += 8) {
        int s0 = esrc[i], s1 = esrc[i + 2], s2 = esrc[i + 4], s3 = esrc[i + 6];
        uint v0 = hb[(size_t)s0 * 32 + c];
        uint v1 = hb[(size_t)s1 * 32 + c];
        uint v2 = hb[(size_t)s2 * 32 + c];
        uint v3 = hb[(size_t)s3 * 32 + c];
        ax += bflo(v0) + bflo(v1);
        ay += bfhi(v0) + bfhi(v1);
        ax += bflo(v2) + bflo(v3);
        ay += bfhi(v2) + bfhi(v3);
    }
    for (; i < end; i += 2) {
        uint v = hb[(size_t)esrc[i] * 32 + c];
        ax += bflo(v); ay += bfhi(v);
    }
    ax += __shfl_xor(ax, 32);
    ay += __shfl_xor(ay, 32);
    if (!half) {
        float dv = dinv[node];
        float2 bv = ((const float2*)b1)[c];
        float rx = fmaxf(fmaf(ax, dv, bv.x), 0.f);
        float ry = fmaxf(fmaf(ay, dv, bv.y), 0.f);
        o1b[(size_t)node * 32 + c] = packbf2(rx, ry);
    }
}

// ===== GEMM2 via MFMA: h2' = dinv * (o1 @ W2), bf16 in, cols padded to 32 =====
// Same structure/fragments as k_gemm1: 64-row tile, 4 waves x 16 rows,
// K=64 (2 steps), 2 col-tiles of 16 (21 real cols + 11 zero).

__global__ __launch_bounds__(256) void k_gemm2m(const uint* __restrict__ o1b, const float* __restrict__ W2,
                                                const float* __restrict__ dinv, uint* __restrict__ h2b, int N) {
    __shared__ ushort_t xs[64 * 136];   // o1 tile bf16 [row][k]
    __shared__ ushort_t ws[32 * 136];   // W2^T bf16 [col][k], cols >= NOUT are 0
    int tid = threadIdx.x;
    int r0 = blockIdx.x * 64;

    // stage W2^T: thread t -> col = t&31, kb = (t>>5)*8 (8 k-values)
    {
        int col = tid & 31;
        int kb = (tid >> 5) * 8;
#pragma unroll
        for (int kk = 0; kk < 8; kk += 2) {
            float a = (col < NOUT) ? W2[(size_t)(kb + kk) * NOUT + col] : 0.f;
            float b = (col < NOUT) ? W2[(size_t)(kb + kk + 1) * NOUT + col] : 0.f;
            *(uint*)&ws[col * 136 + kb + kk] = packbf2(a, b);
        }
    }
    // stage o1 tile: thread t -> row = t>>2, quarter q = t&3 (8 uints = 16 bf16)
    {
        int row = tid >> 2;
        int q = tid & 3;
        int grow = r0 + row;
        uint4 v0 = make_uint4(0u, 0u, 0u, 0u), v1 = v0;
        if (grow < N) {
            const uint4* sp = (const uint4*)(o1b + (size_t)grow * 32 + q * 8);
            v0 = sp[0]; v1 = sp[1];
        }
        uint* d = (uint*)&xs[row * 136 + q * 16];
        ((uint4*)d)[0] = v0;
        ((uint4*)d)[1] = v1;
    }
    __syncthreads();

    int lane = tid & 63;
    int wrow = (tid >> 6) * 16;
    int lrow = lane & 15;
    int lk   = (lane >> 4) * 8;

    f32x4 acc[2];
#pragma unroll
    for (int nt = 0; nt < 2; ++nt) acc[nt] = (f32x4){0.f, 0.f, 0.f, 0.f};

#pragma unroll
    for (int kq = 0; kq < 2; ++kq) {
        int k0 = kq * 32;
        bf16x8 a = *(const bf16x8*)&xs[(wrow + lrow) * 136 + k0 + lk];
#pragma unroll
        for (int nt = 0; nt < 2; ++nt) {
            bf16x8 b = *(const bf16x8*)&ws[(nt * 16 + lrow) * 136 + k0 + lk];
            acc[nt] = __builtin_amdgcn_mfma_f32_16x16x32_bf16(a, b, acc[nt], 0, 0, 0);
        }
    }

    int orow0 = (lane >> 4) * 4;
    float dvv[4];
#pragma unroll
    for (int r = 0; r < 4; ++r) {
        int grow = r0 + wrow + orow0 + r;
        dvv[r] = (grow < N) ? dinv[grow] : 0.f;
    }
    ushort_t* h2s = (ushort_t*)h2b;
#pragma unroll
    for (int nt = 0; nt < 2; ++nt) {
#pragma unroll
        for (int r = 0; r < 4; ++r) {
            int grow = r0 + wrow + orow0 + r;
            if (grow < N) {
                uint pb = packbf2(acc[nt][r] * dvv[r], 0.f);
                h2s[(size_t)grow * 32 + nt * 16 + lrow] = (ushort_t)(pb & 0xffffu);
            }
        }
    }
}

// ===== agg2: out[d] = b2 + dv_d*(h2'[d] + sum_e h2'[src_e]) =====

__global__ __launch_bounds__(256) void k_agg2(const int* __restrict__ rowptr, const int* __restrict__ esrc,
                                              const uint* __restrict__ h2b, const float* __restrict__ dinv,
                                              const float* __restrict__ b2, float* __restrict__ out, int N) {
    int tid = threadIdx.x;
    int node = blockIdx.x * 64 + (tid >> 2);
    if (node >= N) return;
    int q = tid & 3;
    uint4 sv = *((const uint4*)(h2b + (size_t)node * 16) + q);
    float a0 = bflo(sv.x), a1 = bfhi(sv.x), a2 = bflo(sv.y), a3 = bfhi(sv.y);
    float a4 = bflo(sv.z), a5 = bfhi(sv.z), a6 = bflo(sv.w), a7 = bfhi(sv.w);
    int beg = rowptr[node], end = rowptr[node + 1];
    int i = beg;
    for (; i + 3 < end; i += 4) {
        int s0 = esrc[i], s1 = esrc[i + 1], s2 = esrc[i + 2], s3 = esrc[i + 3];
        uint4 v0 = *((const uint4*)(h2b + (size_t)s0 * 16) + q);
        uint4 v1 = *((const uint4*)(h2b + (size_t)s1 * 16) + q);
        uint4 v2 = *((const uint4*)(h2b + (size_t)s2 * 16) + q);
        uint4 v3 = *((const uint4*)(h2b + (size_t)s3 * 16) + q);
        a0 += bflo(v0.x) + bflo(v1.x);
        a1 += bfhi(v0.x) + bfhi(v1.x);
        a2 += bflo(v0.y) + bflo(v1.y);
        a3 += bfhi(v0.y) + bfhi(v1.y);
        a4 += bflo(v0.z) + bflo(v1.z);
        a5 += bfhi(v0.z) + bfhi(v1.z);
        a6 += bflo(v0.w) + bflo(v1.w);
        a7 += bfhi(v0.w) + bfhi(v1.w);
        a0 += bflo(v2.x) + bflo(v3.x);
        a1 += bfhi(v2.x) + bfhi(v3.x);
        a2 += bflo(v2.y) + bflo(v3.y);
        a3 += bfhi(v2.y) + bfhi(v3.y);
        a4 += bflo(v2.z) + bflo(v3.z);
        a5 += bfhi(v2.z) + bfhi(v3.z);
        a6 += bflo(v2.w) + bflo(v3.w);
        a7 += bfhi(v2.w) + bfhi(v3.w);
    }
    for (; i < end; ++i) {
        uint4 v0 = *((const uint4*)(h2b + (size_t)esrc[i] * 16) + q);
        a0 += bflo(v0.x); a1 += bfhi(v0.x);
        a2 += bflo(v0.y); a3 += bfhi(v0.y);
        a4 += bflo(v0.z); a5 += bfhi(v0.z);
        a6 += bflo(v0.w); a7 += bfhi(v0.w);
    }
    float dv = dinv[node];
    float* orow = out + (size_t)node * NOUT;
    int col = q * 8;
    float av[8] = {a0, a1, a2, a3, a4, a5, a6, a7};
#pragma unroll
    for (int j = 0; j < 8; ++j)
        if (col + j < NOUT) orow[col + j] = fmaf(dv, av[j], b2[col + j]);
}

// ================= launch =================

extern "C" void kernel_launch(void* const* d_in, const int* in_sizes, int n_in,
                              void* d_out, int out_size, void* d_ws, size_t ws_size,
                              hipStream_t stream) {
    const float* x  = (const float*)d_in[0];
    const int*   ei = (const int*)d_in[1];
    const float* W1 = (const float*)d_in[2];
    const float* b1 = (const float*)d_in[3];
    const float* W2 = (const float*)d_in[4];
    const float* b2 = (const float*)d_in[5];
    float* out = (float*)d_out;

    int N = in_sizes[0] / NFEAT;
    int E = in_sizes[1] / 2;
    const int* src = ei;
    const int* dst = ei + E;
    int NBUK = (N + (1 << BSH) - 1) >> BSH;
    int NCHUNK = (E + CHUNK - 1) / CHUNK;

    char* p = (char*)d_ws;
    auto alloc = [&](size_t bytes) { void* r = (void*)p; p += (bytes + 255) & ~(size_t)255; return r; };
    int*   rowptr = (int*)alloc((size_t)(N + 1) * 4);
    int*   gcnt   = (int*)alloc((size_t)NBUK * PADI * 4);
    int*   bbase  = (int*)alloc((size_t)NBUK * 4);
    int*   tab    = (int*)alloc((size_t)NCHUNK * (NBUK + 1) * 4);
    uint*  ebuf   = (uint*)alloc((size_t)E * 4);
    int*   esrc   = (int*)alloc((size_t)E * 4);
    float* dinv   = (float*)alloc((size_t)N * 4);
    uint*  hb     = (uint*)alloc((size_t)N * 32 * 4);   // h'  bf16 [N][64]
    uint*  o1b    = (uint*)alloc((size_t)N * 32 * 4);   // o1  bf16 [N][64]
    uint*  h2b    = (uint*)alloc((size_t)N * 16 * 4);   // h2' bf16 [N][32] (padded)
    int*   cnt    = (int*)alloc((size_t)N * 4);      // fallback only
    int*   fill   = (int*)alloc((size_t)N * 4);      // fallback only
    int*   bsum   = (int*)alloc(128 * 4);            // fallback only

    const int B = 256;

    if (N <= (1 << 17)) {
        hipMemsetAsync(gcnt, 0, (size_t)NBUK * PADI * 4, stream);
        k_lsort <<<NCHUNK, 256, 0, stream>>>(src, dst, ebuf, tab, gcnt, E, NBUK);
        k_bscan <<<1, 256, 0, stream>>>(gcnt, bbase, rowptr, NBUK, N, E);
        k_bsort2<<<NBUK, 256, 0, stream>>>(ebuf, tab, bbase, gcnt, rowptr, dinv, esrc, NCHUNK, NBUK, N);
    } else {
        int nb = (N + 1023) / 1024;
        hipMemsetAsync(cnt, 0, (size_t)N * 4, stream);
        k_count <<<(E + B - 1) / B, B, 0, stream>>>(dst, cnt, E);
        k_scan1 <<<nb, 256, 0, stream>>>(cnt, rowptr, bsum, dinv, N);
        k_scan2 <<<1, 128, 0, stream>>>(bsum, nb);
        k_scan3 <<<nb, 256, 0, stream>>>(rowptr, fill, bsum, N, E);
        k_scatter_direct<<<(E + B - 1) / B, B, 0, stream>>>(src, dst, fill, esrc, E);
    }

    k_gemm1 <<<(N + 63) / 64, 256, 0, stream>>>(x, W1, dinv, hb, N);
    k_agg1  <<<(N + 3) / 4, 256, 0, stream>>>(rowptr, esrc, hb, dinv, b1, o1b, N);
    k_gemm2m<<<(N + 63) / 64, 256, 0, stream>>>(o1b, W2, dinv, h2b, N);
    k_agg2  <<<(N + 63) / 64, 256, 0, stream>>>(rowptr, esrc, h2b, dinv, b2, out, N);
}

// Round 14
// 163.457 us; speedup vs baseline: 1.1162x; 1.0065x over previous
//
#include <hip/hip_runtime.h>

#define NFEAT 128
#define NHID  64
#define NOUT  21
#define BSH   7            // 128 nodes / bucket
#define BCAP  8192         // max edges LDS-sorted per bucket
#define CHUNK 4096         // edges per sort block (16 KB private region)
#define EPT   16           // edges per thread in k_lsort
#define PADI  16           // ints per padded counter (64 B)
#define NBUKMAX 1024       // nbuk ceiling for the packed path (N <= 2^17)

typedef unsigned int uint;
typedef unsigned short ushort_t;

typedef __bf16 bf16_t;
typedef bf16_t bf16x8 __attribute__((ext_vector_type(8)));
typedef float  f32x4  __attribute__((ext_vector_type(4)));

// bf16 pack/unpack (RTN-even)
__device__ inline uint packbf2(float a, float b) {
    uint ua = __float_as_uint(a), ub = __float_as_uint(b);
    ua = (ua + 0x7FFFu + ((ua >> 16) & 1u)) >> 16;
    ub = (ub + 0x7FFFu + ((ub >> 16) & 1u)) >> 16;
    return ua | (ub << 16);
}
__device__ inline float bflo(uint v) { return __uint_as_float(v << 16); }
__device__ inline float bfhi(uint v) { return __uint_as_float(v & 0xffff0000u); }

// ============ pass A: per-chunk LDS counting sort by bucket ============
// int4 edge reads, uint4 flush.

__global__ __launch_bounds__(256) void k_lsort(const int* __restrict__ src, const int* __restrict__ dst,
                                               uint* __restrict__ ebuf, int* __restrict__ tab,
                                               int* __restrict__ gcnt, int E, int nbuk) {
    __shared__ int  lcnt[NBUKMAX + 1];
    __shared__ int  lsum[256];
    __shared__ uint lsorted[CHUNK];
    int c = blockIdx.x, tid = threadIdx.x;
    int base = c * CHUNK;
    int ccnt = min(CHUNK, E - base);

    for (int j = tid; j <= nbuk; j += 256) lcnt[j] = 0;
    __syncthreads();

    int  buk[EPT];
    uint rec[EPT];
#pragma unroll
    for (int g = 0; g < EPT / 4; ++g) {
        int e0 = base + g * 1024 + tid * 4;
        int4 dv, sv;
        if (e0 + 3 < E) {
            dv = *(const int4*)&dst[e0];
            sv = *(const int4*)&src[e0];
        } else {
            dv = make_int4(0, 0, 0, 0); sv = dv;
            if (e0     < E) { dv.x = dst[e0];     sv.x = src[e0]; }
            if (e0 + 1 < E) { dv.y = dst[e0 + 1]; sv.y = src[e0 + 1]; }
            if (e0 + 2 < E) { dv.z = dst[e0 + 2]; sv.z = src[e0 + 2]; }
        }
        int dd[4] = {dv.x, dv.y, dv.z, dv.w};
        int ss[4] = {sv.x, sv.y, sv.z, sv.w};
#pragma unroll
        for (int j = 0; j < 4; ++j) {
            int k = g * 4 + j;
            buk[k] = -1;
            if (e0 + j < E) {
                buk[k] = dd[j] >> BSH;
                rec[k] = ((uint)(dd[j] & ((1 << BSH) - 1)) << 17) | (uint)ss[j];
                atomicAdd(&lcnt[buk[k]], 1);
            }
        }
    }
    __syncthreads();

    int g = (nbuk + 255) / 256;
    int j0 = tid * g;
    int s = 0;
    for (int j = 0; j < g; ++j) { int idx = j0 + j; if (idx < nbuk) s += lcnt[idx]; }
    lsum[tid] = s;
    __syncthreads();
    for (int off = 1; off < 256; off <<= 1) {
        int t = (tid >= off) ? lsum[tid - off] : 0;
        __syncthreads();
        lsum[tid] += t;
        __syncthreads();
    }
    int run = lsum[tid] - s;
    for (int j = 0; j < g; ++j) {
        int idx = j0 + j;
        if (idx < nbuk) { int cv = lcnt[idx]; lcnt[idx] = run; run += cv; }
    }
    __syncthreads();
    if (tid == 0) lcnt[nbuk] = ccnt;
    __syncthreads();

    for (int j = tid; j < nbuk; j += 256) {
        int st = lcnt[j];
        tab[(size_t)c * (nbuk + 1) + j] = st;
        int cj = lcnt[j + 1] - st;
        if (cj) atomicAdd(&gcnt[j * PADI], cj);
    }
    if (tid == 0) tab[(size_t)c * (nbuk + 1) + nbuk] = ccnt;
    __syncthreads();

#pragma unroll
    for (int k = 0; k < EPT; ++k) {
        if (buk[k] >= 0) {
            int pos = atomicAdd(&lcnt[buk[k]], 1);
            lsorted[pos] = rec[k];
        }
    }
    __syncthreads();
    // vectorized flush
    for (int i = tid * 4; i + 3 < ccnt; i += 1024)
        *(uint4*)&ebuf[base + i] = *(uint4*)&lsorted[i];
    int tail = ccnt & ~3;
    for (int i = tail + tid; i < ccnt; i += 256) ebuf[base + i] = lsorted[i];
}

// ============ pass B: single-ebuf-pass bucket sort (bscan fused) ============

__global__ __launch_bounds__(256) void k_bsort2(const uint* __restrict__ ebuf, const int* __restrict__ tab,
                                                const int* __restrict__ gcnt,
                                                int* __restrict__ rowptr, float* __restrict__ dinv,
                                                int* __restrict__ esrc, int nchunk, int nbuk, int N, int E) {
    __shared__ int  ncnt[128];
    __shared__ int  sc[128];
    __shared__ int  lcur[128];
    __shared__ int  rsum[256];
    __shared__ uint stash[BCAP];
    __shared__ int  lpos;
    int b = blockIdx.x, tid = threadIdx.x;
    int nb0 = b << BSH;
    int cnt_b = gcnt[b * PADI];
    bool fits = (cnt_b <= BCAP);

    // fused prefix: bb = sum_{j<b} gcnt[j]
    int ps = 0;
    for (int j = tid; j < b; j += 256) ps += gcnt[j * PADI];
    rsum[tid] = ps;
    __syncthreads();
    for (int off = 128; off >= 1; off >>= 1) {
        if (tid < off) rsum[tid] += rsum[tid + off];
        __syncthreads();
    }
    int bb = rsum[0];

    if (tid < 128) ncnt[tid] = 0;
    if (tid == 0) {
        lpos = 0;
        if (b == nbuk - 1) rowptr[N] = E;
    }
    __syncthreads();

    // pass A: slices -> stash + per-node histogram
    for (int c = tid; c < nchunk; c += 256) {
        const int* trow = tab + (size_t)c * (nbuk + 1);
        int s0 = trow[b], e0 = trow[b + 1];
        int len = e0 - s0;
        if (len <= 0) continue;
        const uint* pb = ebuf + (size_t)c * CHUNK;
        if (fits) {
            int pos = atomicAdd(&lpos, len);
            for (int i = 0; i < len; ++i) {
                uint r = pb[s0 + i];
                stash[pos + i] = r;
                atomicAdd(&ncnt[r >> 17], 1);
            }
        } else {
            for (int i = 0; i < len; ++i) atomicAdd(&ncnt[pb[s0 + i] >> 17], 1);
        }
    }
    __syncthreads();

    // exclusive scan over 128 node counts
    int v = (tid < 128) ? ncnt[tid] : 0;
    if (tid < 128) sc[tid] = v;
    __syncthreads();
    for (int off = 1; off < 128; off <<= 1) {
        int t = (tid >= off && tid < 128) ? sc[tid - off] : 0;
        __syncthreads();
        if (tid < 128) sc[tid] += t;
        __syncthreads();
    }
    if (tid < 128) {
        int excl = sc[tid] - v;
        int node = nb0 + tid;
        if (node < N) {
            rowptr[node] = bb + excl;
            dinv[node] = rsqrtf((float)(v + 1));
        }
        lcur[tid] = bb + excl;
    }
    __syncthreads();

    // pass B: place
    if (fits) {
        for (int i = tid; i < cnt_b; i += 256) {
            uint r = stash[i];
            int pos = atomicAdd(&lcur[r >> 17], 1);
            esrc[pos] = (int)(r & 0x1FFFFu);
        }
    } else {
        for (int c = tid; c < nchunk; c += 256) {
            const int* trow = tab + (size_t)c * (nbuk + 1);
            int s0 = trow[b], e0 = trow[b + 1];
            const uint* pb = ebuf + (size_t)c * CHUNK;
            for (int i = s0; i < e0; ++i) {
                uint r = pb[i];
                int pos = atomicAdd(&lcur[r >> 17], 1);
                esrc[pos] = (int)(r & 0x1FFFFu);
            }
        }
    }
}

// ============ general-N fallback (N > 2^17) ============

__global__ __launch_bounds__(256) void k_count(const int* __restrict__ dst, int* cnt, int E) {
    int e = blockIdx.x * 256 + threadIdx.x;
    if (e < E) atomicAdd(&cnt[dst[e]], 1);
}

__global__ __launch_bounds__(256) void k_scan1(const int* __restrict__ cnt, int* __restrict__ rowptr,
                                               int* __restrict__ bsum, float* __restrict__ dinv, int N) {
    __shared__ int sh[256];
    int tid = threadIdx.x;
    int base = blockIdx.x * 1024 + tid * 4;
    int v[4]; int s = 0;
#pragma unroll
    for (int j = 0; j < 4; ++j) {
        v[j] = (base + j < N) ? cnt[base + j] : 0;
        if (base + j < N) dinv[base + j] = rsqrtf((float)(v[j] + 1));
        s += v[j];
    }
    sh[tid] = s; __syncthreads();
    for (int off = 1; off < 256; off <<= 1) {
        int t = (tid >= off) ? sh[tid - off] : 0;
        __syncthreads();
        sh[tid] += t;
        __syncthreads();
    }
    int run = sh[tid] - s;
#pragma unroll
    for (int j = 0; j < 4; ++j) { if (base + j < N) rowptr[base + j] = run; run += v[j]; }
    if (tid == 255) bsum[blockIdx.x] = sh[255];
}

__global__ __launch_bounds__(128) void k_scan2(int* bsum, int nb) {
    __shared__ int sh[128];
    int tid = threadIdx.x;
    int v = (tid < nb) ? bsum[tid] : 0;
    sh[tid] = v; __syncthreads();
    for (int off = 1; off < 128; off <<= 1) {
        int t = (tid >= off) ? sh[tid - off] : 0;
        __syncthreads();
        sh[tid] += t;
        __syncthreads();
    }
    if (tid < nb) bsum[tid] = sh[tid] - v;
}

__global__ __launch_bounds__(256) void k_scan3(int* __restrict__ rowptr, int* __restrict__ fill,
                                               const int* __restrict__ bsum, int N, int E) {
    int tid = threadIdx.x;
    int base = blockIdx.x * 1024 + tid * 4;
    int add = bsum[blockIdx.x];
#pragma unroll
    for (int j = 0; j < 4; ++j) {
        int idx = base + j;
        if (idx < N) {
            int r = rowptr[idx] + add;
            rowptr[idx] = r;
            fill[idx] = r;
        }
    }
    if (blockIdx.x == 0 && tid == 0) rowptr[N] = E;
}

__global__ __launch_bounds__(256) void k_scatter_direct(const int* __restrict__ src, const int* __restrict__ dst,
                                                        int* __restrict__ fill, int* __restrict__ esrc, int E) {
    int e = blockIdx.x * 256 + threadIdx.x;
    if (e >= E) return;
    int pos = atomicAdd(&fill[dst[e]], 1);
    esrc[pos] = src[e];
}

// ===== GEMM1 via MFMA: h' = dinv * (x @ W1), 128-row tile, bf16 out =====
// 4 waves; wave owns 32 rows (2 x 16-row sub-tiles); W1^T staged once.

__global__ __launch_bounds__(256) void k_gemm1(const float* __restrict__ x, const float* __restrict__ W1,
                                               const float* __restrict__ dinv, uint* __restrict__ hb, int N) {
    __shared__ ushort_t xs[128 * 136];  // 34.8 KB
    __shared__ ushort_t ws[64 * 136];   // 17.4 KB
    int tid = threadIdx.x;
    int r0 = blockIdx.x * 128;

    // stage W1^T: col = tid&63, k-range (tid>>6)*32
    {
        int col = tid & 63;
        int kb = (tid >> 6) * 32;
#pragma unroll
        for (int kk = 0; kk < 32; kk += 2) {
            float a = W1[(size_t)(kb + kk) * NHID + col];
            float b = W1[(size_t)(kb + kk + 1) * NHID + col];
            *(uint*)&ws[col * 136 + kb + kk] = packbf2(a, b);
        }
    }
    // stage x tile: thread t -> row = t>>1, half h = t&1 (64 floats)
    {
        int row = tid >> 1;
        int h = tid & 1;
        int grow = r0 + row;
        uint buf[32];
        if (grow < N) {
            const float* xr = x + (size_t)grow * NFEAT + h * 64;
#pragma unroll
            for (int j = 0; j < 16; ++j) {
                float4 v = *(const float4*)&xr[j * 4];
                buf[2 * j]     = packbf2(v.x, v.y);
                buf[2 * j + 1] = packbf2(v.z, v.w);
            }
        } else {
#pragma unroll
            for (int j = 0; j < 32; ++j) buf[j] = 0u;
        }
        uint* d = (uint*)&xs[row * 136 + h * 64];
#pragma unroll
        for (int j = 0; j < 8; ++j)
            ((uint4*)d)[j] = make_uint4(buf[4 * j], buf[4 * j + 1], buf[4 * j + 2], buf[4 * j + 3]);
    }
    __syncthreads();

    int lane = tid & 63;
    int w = tid >> 6;                   // wave's 32-row slab
    int lrow = lane & 15;
    int lk   = (lane >> 4) * 8;

    f32x4 acc[2][4];
#pragma unroll
    for (int s = 0; s < 2; ++s)
#pragma unroll
        for (int nt = 0; nt < 4; ++nt) acc[s][nt] = (f32x4){0.f, 0.f, 0.f, 0.f};

#pragma unroll
    for (int kq = 0; kq < 4; ++kq) {
        int k0 = kq * 32;
        bf16x8 a0 = *(const bf16x8*)&xs[(w * 32 + lrow) * 136 + k0 + lk];
        bf16x8 a1 = *(const bf16x8*)&xs[(w * 32 + 16 + lrow) * 136 + k0 + lk];
#pragma unroll
        for (int nt = 0; nt < 4; ++nt) {
            bf16x8 b = *(const bf16x8*)&ws[(nt * 16 + lrow) * 136 + k0 + lk];
            acc[0][nt] = __builtin_amdgcn_mfma_f32_16x16x32_bf16(a0, b, acc[0][nt], 0, 0, 0);
            acc[1][nt] = __builtin_amdgcn_mfma_f32_16x16x32_bf16(a1, b, acc[1][nt], 0, 0, 0);
        }
    }

    int orow0 = (lane >> 4) * 4;
    ushort_t* hbs = (ushort_t*)hb;
#pragma unroll
    for (int s = 0; s < 2; ++s) {
        float dvv[4];
#pragma unroll
        for (int r = 0; r < 4; ++r) {
            int grow = r0 + w * 32 + s * 16 + orow0 + r;
            dvv[r] = (grow < N) ? dinv[grow] : 0.f;
        }
#pragma unroll
        for (int nt = 0; nt < 4; ++nt) {
#pragma unroll
            for (int r = 0; r < 4; ++r) {
                int grow = r0 + w * 32 + s * 16 + orow0 + r;
                if (grow < N) {
                    uint pb = packbf2(acc[s][nt][r] * dvv[r], 0.f);
                    hbs[(size_t)grow * 64 + nt * 16 + lrow] = (ushort_t)(pb & 0xffffu);
                }
            }
        }
    }
}

// ===== agg1: o1 = relu(b1 + dv*(h'[d] + sum_e h'[src_e])), packed bf16 out =====

__global__ __launch_bounds__(256) void k_agg1(const int* __restrict__ rowptr, const int* __restrict__ esrc,
                                              const uint* __restrict__ hb, const float* __restrict__ dinv,
                                              const float* __restrict__ b1, uint* __restrict__ o1b, int N) {
    int tid = threadIdx.x;
    int node = blockIdx.x * 4 + (tid >> 6);
    if (node >= N) return;
    int lane = tid & 63;
    int half = lane >> 5;
    int c = lane & 31;
    uint sv = hb[(size_t)node * 32 + c];
    float ax = half ? 0.f : bflo(sv);
    float ay = half ? 0.f : bfhi(sv);
    int beg = rowptr[node], end = rowptr[node + 1];
    int i = beg + half;
    for (; i + 14 < end; i += 16) {
        int s0 = esrc[i], s1 = esrc[i + 2], s2 = esrc[i + 4], s3 = esrc[i + 6];
        int s4 = esrc[i + 8], s5 = esrc[i + 10], s6 = esrc[i + 12], s7 = esrc[i + 14];
        uint v0 = hb[(size_t)s0 * 32 + c];
        uint v1 = hb[(size_t)s1 * 32 + c];
        uint v2 = hb[(size_t)s2 * 32 + c];
        uint v3 = hb[(size_t)s3 * 32 + c];
        uint v4 = hb[(size_t)s4 * 32 + c];
        uint v5 = hb[(size_t)s5 * 32 + c];
        uint v6 = hb[(size_t)s6 * 32 + c];
        uint v7 = hb[(size_t)s7 * 32 + c];
        ax += bflo(v0) + bflo(v1);
        ay += bfhi(v0) + bfhi(v1);
        ax += bflo(v2) + bflo(v3);
        ay += bfhi(v2) + bfhi(v3);
        ax += bflo(v4) + bflo(v5);
        ay += bfhi(v4) + bfhi(v5);
        ax += bflo(v6) + bflo(v7);
        ay += bfhi(v6) + bfhi(v7);
    }
    for (; i + 6 < end; i += 8) {
        int s0 = esrc[i], s1 = esrc[i + 2], s2 = esrc[i + 4], s3 = esrc[i + 6];
        uint v0 = hb[(size_t)s0 * 32 + c];
        uint v1 = hb[(size_t)s1 * 32 + c];
        uint v2 = hb[(size_t)s2 * 32 + c];
        uint v3 = hb[(size_t)s3 * 32 + c];
        ax += bflo(v0) + bflo(v1);
        ay += bfhi(v0) + bfhi(v1);
        ax += bflo(v2) + bflo(v3);
        ay += bfhi(v2) + bfhi(v3);
    }
    for (; i < end; i += 2) {
        uint v = hb[(size_t)esrc[i] * 32 + c];
        ax += bflo(v); ay += bfhi(v);
    }
    ax += __shfl_xor(ax, 32);
    ay += __shfl_xor(ay, 32);
    if (!half) {
        float dv = dinv[node];
        float2 bv = ((const float2*)b1)[c];
        float rx = fmaxf(fmaf(ax, dv, bv.x), 0.f);
        float ry = fmaxf(fmaf(ay, dv, bv.y), 0.f);
        o1b[(size_t)node * 32 + c] = packbf2(rx, ry);
    }
}

// ===== GEMM2 via MFMA: h2' = dinv * (o1 @ W2), cols padded to 32 =====

__global__ __launch_bounds__(256) void k_gemm2m(const uint* __restrict__ o1b, const float* __restrict__ W2,
                                                const float* __restrict__ dinv, uint* __restrict__ h2b, int N) {
    __shared__ ushort_t xs[64 * 136];
    __shared__ ushort_t ws[32 * 136];
    int tid = threadIdx.x;
    int r0 = blockIdx.x * 64;

    {
        int col = tid & 31;
        int kb = (tid >> 5) * 8;
#pragma unroll
        for (int kk = 0; kk < 8; kk += 2) {
            float a = (col < NOUT) ? W2[(size_t)(kb + kk) * NOUT + col] : 0.f;
            float b = (col < NOUT) ? W2[(size_t)(kb + kk + 1) * NOUT + col] : 0.f;
            *(uint*)&ws[col * 136 + kb + kk] = packbf2(a, b);
        }
    }
    {
        int row = tid >> 2;
        int q = tid & 3;
        int grow = r0 + row;
        uint4 v0 = make_uint4(0u, 0u, 0u, 0u), v1 = v0;
        if (grow < N) {
            const uint4* sp = (const uint4*)(o1b + (size_t)grow * 32 + q * 8);
            v0 = sp[0]; v1 = sp[1];
        }
        uint* d = (uint*)&xs[row * 136 + q * 16];
        ((uint4*)d)[0] = v0;
        ((uint4*)d)[1] = v1;
    }
    __syncthreads();

    int lane = tid & 63;
    int wrow = (tid >> 6) * 16;
    int lrow = lane & 15;
    int lk   = (lane >> 4) * 8;

    f32x4 acc[2];
#pragma unroll
    for (int nt = 0; nt < 2; ++nt) acc[nt] = (f32x4){0.f, 0.f, 0.f, 0.f};

#pragma unroll
    for (int kq = 0; kq < 2; ++kq) {
        int k0 = kq * 32;
        bf16x8 a = *(const bf16x8*)&xs[(wrow + lrow) * 136 + k0 + lk];
#pragma unroll
        for (int nt = 0; nt < 2; ++nt) {
            bf16x8 b = *(const bf16x8*)&ws[(nt * 16 + lrow) * 136 + k0 + lk];
            acc[nt] = __builtin_amdgcn_mfma_f32_16x16x32_bf16(a, b, acc[nt], 0, 0, 0);
        }
    }

    int orow0 = (lane >> 4) * 4;
    float dvv[4];
#pragma unroll
    for (int r = 0; r < 4; ++r) {
        int grow = r0 + wrow + orow0 + r;
        dvv[r] = (grow < N) ? dinv[grow] : 0.f;
    }
    ushort_t* h2s = (ushort_t*)h2b;
#pragma unroll
    for (int nt = 0; nt < 2; ++nt) {
#pragma unroll
        for (int r = 0; r < 4; ++r) {
            int grow = r0 + wrow + orow0 + r;
            if (grow < N) {
                uint pb = packbf2(acc[nt][r] * dvv[r], 0.f);
                h2s[(size_t)grow * 32 + nt * 16 + lrow] = (ushort_t)(pb & 0xffffu);
            }
        }
    }
}

// ===== agg2: out[d] = b2 + dv_d*(h2'[d] + sum_e h2'[src_e]) =====

__global__ __launch_bounds__(256) void k_agg2(const int* __restrict__ rowptr, const int* __restrict__ esrc,
                                              const uint* __restrict__ h2b, const float* __restrict__ dinv,
                                              const float* __restrict__ b2, float* __restrict__ out, int N) {
    int tid = threadIdx.x;
    int node = blockIdx.x * 64 + (tid >> 2);
    if (node >= N) return;
    int q = tid & 3;
    uint4 sv = *((const uint4*)(h2b + (size_t)node * 16) + q);
    float a0 = bflo(sv.x), a1 = bfhi(sv.x), a2 = bflo(sv.y), a3 = bfhi(sv.y);
    float a4 = bflo(sv.z), a5 = bfhi(sv.z), a6 = bflo(sv.w), a7 = bfhi(sv.w);
    int beg = rowptr[node], end = rowptr[node + 1];
    int i = beg;
    for (; i + 3 < end; i += 4) {
        int s0 = esrc[i], s1 = esrc[i + 1], s2 = esrc[i + 2], s3 = esrc[i + 3];
        uint4 v0 = *((const uint4*)(h2b + (size_t)s0 * 16) + q);
        uint4 v1 = *((const uint4*)(h2b + (size_t)s1 * 16) + q);
        uint4 v2 = *((const uint4*)(h2b + (size_t)s2 * 16) + q);
        uint4 v3 = *((const uint4*)(h2b + (size_t)s3 * 16) + q);
        a0 += bflo(v0.x) + bflo(v1.x);
        a1 += bfhi(v0.x) + bfhi(v1.x);
        a2 += bflo(v0.y) + bflo(v1.y);
        a3 += bfhi(v0.y) + bfhi(v1.y);
        a4 += bflo(v0.z) + bflo(v1.z);
        a5 += bfhi(v0.z) + bfhi(v1.z);
        a6 += bflo(v0.w) + bflo(v1.w);
        a7 += bfhi(v0.w) + bfhi(v1.w);
        a0 += bflo(v2.x) + bflo(v3.x);
        a1 += bfhi(v2.x) + bfhi(v3.x);
        a2 += bflo(v2.y) + bflo(v3.y);
        a3 += bfhi(v2.y) + bfhi(v3.y);
        a4 += bflo(v2.z) + bflo(v3.z);
        a5 += bfhi(v2.z) + bfhi(v3.z);
        a6 += bflo(v2.w) + bflo(v3.w);
        a7 += bfhi(v2.w) + bfhi(v3.w);
    }
    for (; i < end; ++i) {
        uint4 v0 = *((const uint4*)(h2b + (size_t)esrc[i] * 16) + q);
        a0 += bflo(v0.x); a1 += bfhi(v0.x);
        a2 += bflo(v0.y); a3 += bfhi(v0.y);
        a4 += bflo(v0.z); a5 += bfhi(v0.z);
        a6 += bflo(v0.w); a7 += bfhi(v0.w);
    }
    float dv = dinv[node];
    float* orow = out + (size_t)node * NOUT;
    int col = q * 8;
    float av[8] = {a0, a1, a2, a3, a4, a5, a6, a7};
#pragma unroll
    for (int j = 0; j < 8; ++j)
        if (col + j < NOUT) orow[col + j] = fmaf(dv, av[j], b2[col + j]);
}

// ================= launch =================

extern "C" void kernel_launch(void* const* d_in, const int* in_sizes, int n_in,
                              void* d_out, int out_size, void* d_ws, size_t ws_size,
                              hipStream_t stream) {
    const float* x  = (const float*)d_in[0];
    const int*   ei = (const int*)d_in[1];
    const float* W1 = (const float*)d_in[2];
    const float* b1 = (const float*)d_in[3];
    const float* W2 = (const float*)d_in[4];
    const float* b2 = (const float*)d_in[5];
    float* out = (float*)d_out;

    int N = in_sizes[0] / NFEAT;
    int E = in_sizes[1] / 2;
    const int* src = ei;
    const int* dst = ei + E;
    int NBUK = (N + (1 << BSH) - 1) >> BSH;
    int NCHUNK = (E + CHUNK - 1) / CHUNK;

    char* p = (char*)d_ws;
    auto alloc = [&](size_t bytes) { void* r = (void*)p; p += (bytes + 255) & ~(size_t)255; return r; };
    int*   rowptr = (int*)alloc((size_t)(N + 1) * 4);
    int*   gcnt   = (int*)alloc((size_t)NBUK * PADI * 4);
    int*   tab    = (int*)alloc((size_t)NCHUNK * (NBUK + 1) * 4);
    uint*  ebuf   = (uint*)alloc((size_t)E * 4);
    int*   esrc   = (int*)alloc((size_t)E * 4);
    float* dinv   = (float*)alloc((size_t)N * 4);
    uint*  hb     = (uint*)alloc((size_t)N * 32 * 4);   // h'  bf16 [N][64]
    uint*  o1b    = (uint*)alloc((size_t)N * 32 * 4);   // o1  bf16 [N][64]
    uint*  h2b    = (uint*)alloc((size_t)N * 16 * 4);   // h2' bf16 [N][32] (padded)
    int*   cnt    = (int*)alloc((size_t)N * 4);      // fallback only
    int*   fill   = (int*)alloc((size_t)N * 4);      // fallback only
    int*   bsum   = (int*)alloc(128 * 4);            // fallback only

    const int B = 256;

    if (N <= (1 << 17)) {
        hipMemsetAsync(gcnt, 0, (size_t)NBUK * PADI * 4, stream);
        k_lsort <<<NCHUNK, 256, 0, stream>>>(src, dst, ebuf, tab, gcnt, E, NBUK);
        k_bsort2<<<NBUK, 256, 0, stream>>>(ebuf, tab, gcnt, rowptr, dinv, esrc, NCHUNK, NBUK, N, E);
    } else {
        int nb = (N + 1023) / 1024;
        hipMemsetAsync(cnt, 0, (size_t)N * 4, stream);
        k_count <<<(E + B - 1) / B, B, 0, stream>>>(dst, cnt, E);
        k_scan1 <<<nb, 256, 0, stream>>>(cnt, rowptr, bsum, dinv, N);
        k_scan2 <<<1, 128, 0, stream>>>(bsum, nb);
        k_scan3 <<<nb, 256, 0, stream>>>(rowptr, fill, bsum, N, E);
        k_scatter_direct<<<(E + B - 1) / B, B, 0, stream>>>(src, dst, fill, esrc, E);
    }

    k_gemm1 <<<(N + 127) / 128, 256, 0, stream>>>(x, W1, dinv, hb, N);
    k_agg1  <<<(N + 3) / 4, 256, 0, stream>>>(rowptr, esrc, hb, dinv, b1, o1b, N);
    k_gemm2m<<<(N + 63) / 64, 256, 0, stream>>>(o1b, W2, dinv, h2b, N);
    k_agg2  <<<(N + 63) / 64, 256, 0, stream>>>(rowptr, esrc, h2b, dinv, b2, out, N);
}

// Round 15
// 156.995 us; speedup vs baseline: 1.1622x; 1.0412x over previous
//
#include <hip/hip_runtime.h>

#define NFEAT 128
#define NHID  64
#define NOUT  21
#define BSH   7            // 128 nodes / bucket
#define BCAP  8192         // max edges LDS-sorted per bucket
#define CHUNK 4096         // edges per sort block (16 KB private region)
#define EPT   16           // edges per thread in k_lsort
#define PADI  16           // ints per padded counter (64 B)
#define NBUKMAX 1024       // nbuk ceiling for the packed path (N <= 2^17)

typedef unsigned int uint;
typedef unsigned short ushort_t;

typedef __bf16 bf16_t;
typedef bf16_t bf16x8 __attribute__((ext_vector_type(8)));
typedef float  f32x4  __attribute__((ext_vector_type(4)));

// bf16 pack/unpack (RTN-even)
__device__ inline uint packbf2(float a, float b) {
    uint ua = __float_as_uint(a), ub = __float_as_uint(b);
    ua = (ua + 0x7FFFu + ((ua >> 16) & 1u)) >> 16;
    ub = (ub + 0x7FFFu + ((ub >> 16) & 1u)) >> 16;
    return ua | (ub << 16);
}
__device__ inline float bflo(uint v) { return __uint_as_float(v << 16); }
__device__ inline float bfhi(uint v) { return __uint_as_float(v & 0xffff0000u); }

// ============ pass A: per-chunk LDS counting sort by bucket ============

__global__ __launch_bounds__(256) void k_lsort(const int* __restrict__ src, const int* __restrict__ dst,
                                               uint* __restrict__ ebuf, int* __restrict__ tab,
                                               int* __restrict__ gcnt, int E, int nbuk) {
    __shared__ int  lcnt[NBUKMAX + 1];
    __shared__ int  lsum[256];
    __shared__ uint lsorted[CHUNK];
    int c = blockIdx.x, tid = threadIdx.x;
    int base = c * CHUNK;
    int ccnt = min(CHUNK, E - base);

    for (int j = tid; j <= nbuk; j += 256) lcnt[j] = 0;
    __syncthreads();

    int  buk[EPT];
    uint rec[EPT];
#pragma unroll
    for (int g = 0; g < EPT / 4; ++g) {
        int e0 = base + g * 1024 + tid * 4;
        int4 dv, sv;
        if (e0 + 3 < E) {
            dv = *(const int4*)&dst[e0];
            sv = *(const int4*)&src[e0];
        } else {
            dv = make_int4(0, 0, 0, 0); sv = dv;
            if (e0     < E) { dv.x = dst[e0];     sv.x = src[e0]; }
            if (e0 + 1 < E) { dv.y = dst[e0 + 1]; sv.y = src[e0 + 1]; }
            if (e0 + 2 < E) { dv.z = dst[e0 + 2]; sv.z = src[e0 + 2]; }
        }
        int dd[4] = {dv.x, dv.y, dv.z, dv.w};
        int ss[4] = {sv.x, sv.y, sv.z, sv.w};
#pragma unroll
        for (int j = 0; j < 4; ++j) {
            int k = g * 4 + j;
            buk[k] = -1;
            if (e0 + j < E) {
                buk[k] = dd[j] >> BSH;
                rec[k] = ((uint)(dd[j] & ((1 << BSH) - 1)) << 17) | (uint)ss[j];
                atomicAdd(&lcnt[buk[k]], 1);
            }
        }
    }
    __syncthreads();

    int g = (nbuk + 255) / 256;
    int j0 = tid * g;
    int s = 0;
    for (int j = 0; j < g; ++j) { int idx = j0 + j; if (idx < nbuk) s += lcnt[idx]; }
    lsum[tid] = s;
    __syncthreads();
    for (int off = 1; off < 256; off <<= 1) {
        int t = (tid >= off) ? lsum[tid - off] : 0;
        __syncthreads();
        lsum[tid] += t;
        __syncthreads();
    }
    int run = lsum[tid] - s;
    for (int j = 0; j < g; ++j) {
        int idx = j0 + j;
        if (idx < nbuk) { int cv = lcnt[idx]; lcnt[idx] = run; run += cv; }
    }
    __syncthreads();
    if (tid == 0) lcnt[nbuk] = ccnt;
    __syncthreads();

    for (int j = tid; j < nbuk; j += 256) {
        int st = lcnt[j];
        tab[(size_t)c * (nbuk + 1) + j] = st;
        int cj = lcnt[j + 1] - st;
        if (cj) atomicAdd(&gcnt[j * PADI], cj);
    }
    if (tid == 0) tab[(size_t)c * (nbuk + 1) + nbuk] = ccnt;
    __syncthreads();

#pragma unroll
    for (int k = 0; k < EPT; ++k) {
        if (buk[k] >= 0) {
            int pos = atomicAdd(&lcnt[buk[k]], 1);
            lsorted[pos] = rec[k];
        }
    }
    __syncthreads();
    for (int i = tid * 4; i + 3 < ccnt; i += 1024)
        *(uint4*)&ebuf[base + i] = *(uint4*)&lsorted[i];
    int tail = ccnt & ~3;
    for (int i = tail + tid; i < ccnt; i += 256) ebuf[base + i] = lsorted[i];
}

// ============ pass B: single-ebuf-pass bucket sort (bscan fused) ============

__global__ __launch_bounds__(256) void k_bsort2(const uint* __restrict__ ebuf, const int* __restrict__ tab,
                                                const int* __restrict__ gcnt,
                                                int* __restrict__ rowptr, float* __restrict__ dinv,
                                                int* __restrict__ esrc, int nchunk, int nbuk, int N, int E) {
    __shared__ int  ncnt[128];
    __shared__ int  sc[128];
    __shared__ int  lcur[128];
    __shared__ int  rsum[256];
    __shared__ uint stash[BCAP];
    __shared__ int  lpos;
    int b = blockIdx.x, tid = threadIdx.x;
    int nb0 = b << BSH;
    int cnt_b = gcnt[b * PADI];
    bool fits = (cnt_b <= BCAP);

    int ps = 0;
    for (int j = tid; j < b; j += 256) ps += gcnt[j * PADI];
    rsum[tid] = ps;
    __syncthreads();
    for (int off = 128; off >= 1; off >>= 1) {
        if (tid < off) rsum[tid] += rsum[tid + off];
        __syncthreads();
    }
    int bb = rsum[0];

    if (tid < 128) ncnt[tid] = 0;
    if (tid == 0) {
        lpos = 0;
        if (b == nbuk - 1) rowptr[N] = E;
    }
    __syncthreads();

    for (int c = tid; c < nchunk; c += 256) {
        const int* trow = tab + (size_t)c * (nbuk + 1);
        int s0 = trow[b], e0 = trow[b + 1];
        int len = e0 - s0;
        if (len <= 0) continue;
        const uint* pb = ebuf + (size_t)c * CHUNK;
        if (fits) {
            int pos = atomicAdd(&lpos, len);
            for (int i = 0; i < len; ++i) {
                uint r = pb[s0 + i];
                stash[pos + i] = r;
                atomicAdd(&ncnt[r >> 17], 1);
            }
        } else {
            for (int i = 0; i < len; ++i) atomicAdd(&ncnt[pb[s0 + i] >> 17], 1);
        }
    }
    __syncthreads();

    int v = (tid < 128) ? ncnt[tid] : 0;
    if (tid < 128) sc[tid] = v;
    __syncthreads();
    for (int off = 1; off < 128; off <<= 1) {
        int t = (tid >= off && tid < 128) ? sc[tid - off] : 0;
        __syncthreads();
        if (tid < 128) sc[tid] += t;
        __syncthreads();
    }
    if (tid < 128) {
        int excl = sc[tid] - v;
        int node = nb0 + tid;
        if (node < N) {
            rowptr[node] = bb + excl;
            dinv[node] = rsqrtf((float)(v + 1));
        }
        lcur[tid] = bb + excl;
    }
    __syncthreads();

    if (fits) {
        for (int i = tid; i < cnt_b; i += 256) {
            uint r = stash[i];
            int pos = atomicAdd(&lcur[r >> 17], 1);
            esrc[pos] = (int)(r & 0x1FFFFu);
        }
    } else {
        for (int c = tid; c < nchunk; c += 256) {
            const int* trow = tab + (size_t)c * (nbuk + 1);
            int s0 = trow[b], e0 = trow[b + 1];
            const uint* pb = ebuf + (size_t)c * CHUNK;
            for (int i = s0; i < e0; ++i) {
                uint r = pb[i];
                int pos = atomicAdd(&lcur[r >> 17], 1);
                esrc[pos] = (int)(r & 0x1FFFFu);
            }
        }
    }
}

// ============ general-N fallback (N > 2^17) ============

__global__ __launch_bounds__(256) void k_count(const int* __restrict__ dst, int* cnt, int E) {
    int e = blockIdx.x * 256 + threadIdx.x;
    if (e < E) atomicAdd(&cnt[dst[e]], 1);
}

__global__ __launch_bounds__(256) void k_scan1(const int* __restrict__ cnt, int* __restrict__ rowptr,
                                               int* __restrict__ bsum, float* __restrict__ dinv, int N) {
    __shared__ int sh[256];
    int tid = threadIdx.x;
    int base = blockIdx.x * 1024 + tid * 4;
    int v[4]; int s = 0;
#pragma unroll
    for (int j = 0; j < 4; ++j) {
        v[j] = (base + j < N) ? cnt[base + j] : 0;
        if (base + j < N) dinv[base + j] = rsqrtf((float)(v[j] + 1));
        s += v[j];
    }
    sh[tid] = s; __syncthreads();
    for (int off = 1; off < 256; off <<= 1) {
        int t = (tid >= off) ? sh[tid - off] : 0;
        __syncthreads();
        sh[tid] += t;
        __syncthreads();
    }
    int run = sh[tid] - s;
#pragma unroll
    for (int j = 0; j < 4; ++j) { if (base + j < N) rowptr[base + j] = run; run += v[j]; }
    if (tid == 255) bsum[blockIdx.x] = sh[255];
}

__global__ __launch_bounds__(128) void k_scan2(int* bsum, int nb) {
    __shared__ int sh[128];
    int tid = threadIdx.x;
    int v = (tid < nb) ? bsum[tid] : 0;
    sh[tid] = v; __syncthreads();
    for (int off = 1; off < 128; off <<= 1) {
        int t = (tid >= off) ? sh[tid - off] : 0;
        __syncthreads();
        sh[tid] += t;
        __syncthreads();
    }
    if (tid < nb) bsum[tid] = sh[tid] - v;
}

__global__ __launch_bounds__(256) void k_scan3(int* __restrict__ rowptr, int* __restrict__ fill,
                                               const int* __restrict__ bsum, int N, int E) {
    int tid = threadIdx.x;
    int base = blockIdx.x * 1024 + tid * 4;
    int add = bsum[blockIdx.x];
#pragma unroll
    for (int j = 0; j < 4; ++j) {
        int idx = base + j;
        if (idx < N) {
            int r = rowptr[idx] + add;
            rowptr[idx] = r;
            fill[idx] = r;
        }
    }
    if (blockIdx.x == 0 && tid == 0) rowptr[N] = E;
}

__global__ __launch_bounds__(256) void k_scatter_direct(const int* __restrict__ src, const int* __restrict__ dst,
                                                        int* __restrict__ fill, int* __restrict__ esrc, int E) {
    int e = blockIdx.x * 256 + threadIdx.x;
    if (e >= E) return;
    int pos = atomicAdd(&fill[dst[e]], 1);
    esrc[pos] = src[e];
}

// ===== GEMM1 via MFMA: h' = dinv * (x @ W1) =====
// A-fragments loaded DIRECTLY from global x into registers (pack in-reg);
// only W1^T staged in LDS. 64-row tile, 4 waves x 16 rows.

__global__ __launch_bounds__(256) void k_gemm1(const float* __restrict__ x, const float* __restrict__ W1,
                                               const float* __restrict__ dinv, uint* __restrict__ hb, int N) {
    __shared__ ushort_t ws[64 * 136];   // W1^T bf16 [col][k], 17.4 KB
    int tid = threadIdx.x;
    int r0 = blockIdx.x * 64;

    {
        int col = tid & 63;
        int kb = (tid >> 6) * 32;
#pragma unroll
        for (int kk = 0; kk < 32; kk += 2) {
            float a = W1[(size_t)(kb + kk) * NHID + col];
            float b = W1[(size_t)(kb + kk + 1) * NHID + col];
            *(uint*)&ws[col * 136 + kb + kk] = packbf2(a, b);
        }
    }
    __syncthreads();

    int lane = tid & 63;
    int wrow = (tid >> 6) * 16;
    int lrow = lane & 15;
    int lk8  = (lane >> 4) * 8;         // float offset inside 32-float k-window

    int arow = r0 + wrow + lrow;
    bool aok = arow < N;
    const float* xr = x + (size_t)arow * NFEAT;

    f32x4 acc[4];
#pragma unroll
    for (int nt = 0; nt < 4; ++nt) acc[nt] = (f32x4){0.f, 0.f, 0.f, 0.f};

#pragma unroll
    for (int kq = 0; kq < 4; ++kq) {
        int kf = kq * 32 + lk8;
        float4 va = make_float4(0.f, 0.f, 0.f, 0.f), vb = va;
        if (aok) { va = *(const float4*)&xr[kf]; vb = *(const float4*)&xr[kf + 4]; }
        uint4 au = make_uint4(packbf2(va.x, va.y), packbf2(va.z, va.w),
                              packbf2(vb.x, vb.y), packbf2(vb.z, vb.w));
        bf16x8 a = *(bf16x8*)&au;
#pragma unroll
        for (int nt = 0; nt < 4; ++nt) {
            bf16x8 b = *(const bf16x8*)&ws[(nt * 16 + lrow) * 136 + kq * 32 + lk8];
            acc[nt] = __builtin_amdgcn_mfma_f32_16x16x32_bf16(a, b, acc[nt], 0, 0, 0);
        }
    }

    int orow0 = (lane >> 4) * 4;
    float dvv[4];
#pragma unroll
    for (int r = 0; r < 4; ++r) {
        int grow = r0 + wrow + orow0 + r;
        dvv[r] = (grow < N) ? dinv[grow] : 0.f;
    }
    ushort_t* hbs = (ushort_t*)hb;
#pragma unroll
    for (int nt = 0; nt < 4; ++nt) {
#pragma unroll
        for (int r = 0; r < 4; ++r) {
            int grow = r0 + wrow + orow0 + r;
            if (grow < N) {
                uint pb = packbf2(acc[nt][r] * dvv[r], 0.f);
                hbs[(size_t)grow * 64 + nt * 16 + lrow] = (ushort_t)(pb & 0xffffu);
            }
        }
    }
}

// ===== agg1: o1 = relu(b1 + dv*(h'[d] + sum_e h'[src_e])), packed bf16 out =====

__global__ __launch_bounds__(256) void k_agg1(const int* __restrict__ rowptr, const int* __restrict__ esrc,
                                              const uint* __restrict__ hb, const float* __restrict__ dinv,
                                              const float* __restrict__ b1, uint* __restrict__ o1b, int N) {
    int tid = threadIdx.x;
    int node = blockIdx.x * 4 + (tid >> 6);
    if (node >= N) return;
    int lane = tid & 63;
    int half = lane >> 5;
    int c = lane & 31;
    uint sv = hb[(size_t)node * 32 + c];
    float ax = half ? 0.f : bflo(sv);
    float ay = half ? 0.f : bfhi(sv);
    int beg = rowptr[node], end = rowptr[node + 1];
    int i = beg + half;
    for (; i + 14 < end; i += 16) {
        int s0 = esrc[i], s1 = esrc[i + 2], s2 = esrc[i + 4], s3 = esrc[i + 6];
        int s4 = esrc[i + 8], s5 = esrc[i + 10], s6 = esrc[i + 12], s7 = esrc[i + 14];
        uint v0 = hb[(size_t)s0 * 32 + c];
        uint v1 = hb[(size_t)s1 * 32 + c];
        uint v2 = hb[(size_t)s2 * 32 + c];
        uint v3 = hb[(size_t)s3 * 32 + c];
        uint v4 = hb[(size_t)s4 * 32 + c];
        uint v5 = hb[(size_t)s5 * 32 + c];
        uint v6 = hb[(size_t)s6 * 32 + c];
        uint v7 = hb[(size_t)s7 * 32 + c];
        ax += bflo(v0) + bflo(v1);
        ay += bfhi(v0) + bfhi(v1);
        ax += bflo(v2) + bflo(v3);
        ay += bfhi(v2) + bfhi(v3);
        ax += bflo(v4) + bflo(v5);
        ay += bfhi(v4) + bfhi(v5);
        ax += bflo(v6) + bflo(v7);
        ay += bfhi(v6) + bfhi(v7);
    }
    for (; i + 6 < end; i += 8) {
        int s0 = esrc[i], s1 = esrc[i + 2], s2 = esrc[i + 4], s3 = esrc[i + 6];
        uint v0 = hb[(size_t)s0 * 32 + c];
        uint v1 = hb[(size_t)s1 * 32 + c];
        uint v2 = hb[(size_t)s2 * 32 + c];
        uint v3 = hb[(size_t)s3 * 32 + c];
        ax += bflo(v0) + bflo(v1);
        ay += bfhi(v0) + bfhi(v1);
        ax += bflo(v2) + bflo(v3);
        ay += bfhi(v2) + bfhi(v3);
    }
    for (; i < end; i += 2) {
        uint v = hb[(size_t)esrc[i] * 32 + c];
        ax += bflo(v); ay += bfhi(v);
    }
    ax += __shfl_xor(ax, 32);
    ay += __shfl_xor(ay, 32);
    if (!half) {
        float dv = dinv[node];
        float2 bv = ((const float2*)b1)[c];
        float rx = fmaxf(fmaf(ax, dv, bv.x), 0.f);
        float ry = fmaxf(fmaf(ay, dv, bv.y), 0.f);
        o1b[(size_t)node * 32 + c] = packbf2(rx, ry);
    }
}

// ===== GEMM2 via MFMA: h2' = dinv * (o1 @ W2), cols padded to 32 =====
// A-fragments read directly from o1b (already bf16, 16 B/lane); W2^T in LDS.

__global__ __launch_bounds__(256) void k_gemm2m(const uint* __restrict__ o1b, const float* __restrict__ W2,
                                                const float* __restrict__ dinv, uint* __restrict__ h2b, int N) {
    __shared__ ushort_t ws[32 * 136];   // 8.7 KB
    int tid = threadIdx.x;
    int r0 = blockIdx.x * 64;

    {
        int col = tid & 31;
        int kb = (tid >> 5) * 8;
#pragma unroll
        for (int kk = 0; kk < 8; kk += 2) {
            float a = (col < NOUT) ? W2[(size_t)(kb + kk) * NOUT + col] : 0.f;
            float b = (col < NOUT) ? W2[(size_t)(kb + kk + 1) * NOUT + col] : 0.f;
            *(uint*)&ws[col * 136 + kb + kk] = packbf2(a, b);
        }
    }
    __syncthreads();

    int lane = tid & 63;
    int wrow = (tid >> 6) * 16;
    int lrow = lane & 15;
    int lk8  = (lane >> 4) * 8;         // bf16 offset inside 32-bf16 k-window

    int arow = r0 + wrow + lrow;
    bool aok = arow < N;
    const ushort_t* orp = (const ushort_t*)o1b + (size_t)arow * 64;

    f32x4 acc[2];
#pragma unroll
    for (int nt = 0; nt < 2; ++nt) acc[nt] = (f32x4){0.f, 0.f, 0.f, 0.f};

#pragma unroll
    for (int kq = 0; kq < 2; ++kq) {
        uint4 au = make_uint4(0u, 0u, 0u, 0u);
        if (aok) au = *(const uint4*)&orp[kq * 32 + lk8];
        bf16x8 a = *(bf16x8*)&au;
#pragma unroll
        for (int nt = 0; nt < 2; ++nt) {
            bf16x8 b = *(const bf16x8*)&ws[(nt * 16 + lrow) * 136 + kq * 32 + lk8];
            acc[nt] = __builtin_amdgcn_mfma_f32_16x16x32_bf16(a, b, acc[nt], 0, 0, 0);
        }
    }

    int orow0 = (lane >> 4) * 4;
    float dvv[4];
#pragma unroll
    for (int r = 0; r < 4; ++r) {
        int grow = r0 + wrow + orow0 + r;
        dvv[r] = (grow < N) ? dinv[grow] : 0.f;
    }
    ushort_t* h2s = (ushort_t*)h2b;
#pragma unroll
    for (int nt = 0; nt < 2; ++nt) {
#pragma unroll
        for (int r = 0; r < 4; ++r) {
            int grow = r0 + wrow + orow0 + r;
            if (grow < N) {
                uint pb = packbf2(acc[nt][r] * dvv[r], 0.f);
                h2s[(size_t)grow * 32 + nt * 16 + lrow] = (ushort_t)(pb & 0xffffu);
            }
        }
    }
}

// ===== agg2: out[d] = b2 + dv_d*(h2'[d] + sum_e h2'[src_e]) =====

__global__ __launch_bounds__(256) void k_agg2(const int* __restrict__ rowptr, const int* __restrict__ esrc,
                                              const uint* __restrict__ h2b, const float* __restrict__ dinv,
                                              const float* __restrict__ b2, float* __restrict__ out, int N) {
    int tid = threadIdx.x;
    int node = blockIdx.x * 64 + (tid >> 2);
    if (node >= N) return;
    int q = tid & 3;
    uint4 sv = *((const uint4*)(h2b + (size_t)node * 16) + q);
    float a0 = bflo(sv.x), a1 = bfhi(sv.x), a2 = bflo(sv.y), a3 = bfhi(sv.y);
    float a4 = bflo(sv.z), a5 = bfhi(sv.z), a6 = bflo(sv.w), a7 = bfhi(sv.w);
    int beg = rowptr[node], end = rowptr[node + 1];
    int i = beg;
    for (; i + 3 < end; i += 4) {
        int s0 = esrc[i], s1 = esrc[i + 1], s2 = esrc[i + 2], s3 = esrc[i + 3];
        uint4 v0 = *((const uint4*)(h2b + (size_t)s0 * 16) + q);
        uint4 v1 = *((const uint4*)(h2b + (size_t)s1 * 16) + q);
        uint4 v2 = *((const uint4*)(h2b + (size_t)s2 * 16) + q);
        uint4 v3 = *((const uint4*)(h2b + (size_t)s3 * 16) + q);
        a0 += bflo(v0.x) + bflo(v1.x);
        a1 += bfhi(v0.x) + bfhi(v1.x);
        a2 += bflo(v0.y) + bflo(v1.y);
        a3 += bfhi(v0.y) + bfhi(v1.y);
        a4 += bflo(v0.z) + bflo(v1.z);
        a5 += bfhi(v0.z) + bfhi(v1.z);
        a6 += bflo(v0.w) + bflo(v1.w);
        a7 += bfhi(v0.w) + bfhi(v1.w);
        a0 += bflo(v2.x) + bflo(v3.x);
        a1 += bfhi(v2.x) + bfhi(v3.x);
        a2 += bflo(v2.y) + bflo(v3.y);
        a3 += bfhi(v2.y) + bfhi(v3.y);
        a4 += bflo(v2.z) + bflo(v3.z);
        a5 += bfhi(v2.z) + bfhi(v3.z);
        a6 += bflo(v2.w) + bflo(v3.w);
        a7 += bfhi(v2.w) + bfhi(v3.w);
    }
    for (; i < end; ++i) {
        uint4 v0 = *((const uint4*)(h2b + (size_t)esrc[i] * 16) + q);
        a0 += bflo(v0.x); a1 += bfhi(v0.x);
        a2 += bflo(v0.y); a3 += bfhi(v0.y);
        a4 += bflo(v0.z); a5 += bfhi(v0.z);
        a6 += bflo(v0.w); a7 += bfhi(v0.w);
    }
    float dv = dinv[node];
    float* orow = out + (size_t)node * NOUT;
    int col = q * 8;
    float av[8] = {a0, a1, a2, a3, a4, a5, a6, a7};
#pragma unroll
    for (int j = 0; j < 8; ++j)
        if (col + j < NOUT) orow[col + j] = fmaf(dv, av[j], b2[col + j]);
}

// ================= launch =================

extern "C" void kernel_launch(void* const* d_in, const int* in_sizes, int n_in,
                              void* d_out, int out_size, void* d_ws, size_t ws_size,
                              hipStream_t stream) {
    const float* x  = (const float*)d_in[0];
    const int*   ei = (const int*)d_in[1];
    const float* W1 = (const float*)d_in[2];
    const float* b1 = (const float*)d_in[3];
    const float* W2 = (const float*)d_in[4];
    const float* b2 = (const float*)d_in[5];
    float* out = (float*)d_out;

    int N = in_sizes[0] / NFEAT;
    int E = in_sizes[1] / 2;
    const int* src = ei;
    const int* dst = ei + E;
    int NBUK = (N + (1 << BSH) - 1) >> BSH;
    int NCHUNK = (E + CHUNK - 1) / CHUNK;

    char* p = (char*)d_ws;
    auto alloc = [&](size_t bytes) { void* r = (void*)p; p += (bytes + 255) & ~(size_t)255; return r; };
    int*   rowptr = (int*)alloc((size_t)(N + 1) * 4);
    int*   gcnt   = (int*)alloc((size_t)NBUK * PADI * 4);
    int*   tab    = (int*)alloc((size_t)NCHUNK * (NBUK + 1) * 4);
    uint*  ebuf   = (uint*)alloc((size_t)E * 4);
    int*   esrc   = (int*)alloc((size_t)E * 4);
    float* dinv   = (float*)alloc((size_t)N * 4);
    uint*  hb     = (uint*)alloc((size_t)N * 32 * 4);   // h'  bf16 [N][64]
    uint*  o1b    = (uint*)alloc((size_t)N * 32 * 4);   // o1  bf16 [N][64]
    uint*  h2b    = (uint*)alloc((size_t)N * 16 * 4);   // h2' bf16 [N][32] (padded)
    int*   cnt    = (int*)alloc((size_t)N * 4);      // fallback only
    int*   fill   = (int*)alloc((size_t)N * 4);      // fallback only
    int*   bsum   = (int*)alloc(128 * 4);            // fallback only

    const int B = 256;

    if (N <= (1 << 17)) {
        hipMemsetAsync(gcnt, 0, (size_t)NBUK * PADI * 4, stream);
        k_lsort <<<NCHUNK, 256, 0, stream>>>(src, dst, ebuf, tab, gcnt, E, NBUK);
        k_bsort2<<<NBUK, 256, 0, stream>>>(ebuf, tab, gcnt, rowptr, dinv, esrc, NCHUNK, NBUK, N, E);
    } else {
        int nb = (N + 1023) / 1024;
        hipMemsetAsync(cnt, 0, (size_t)N * 4, stream);
        k_count <<<(E + B - 1) / B, B, 0, stream>>>(dst, cnt, E);
        k_scan1 <<<nb, 256, 0, stream>>>(cnt, rowptr, bsum, dinv, N);
        k_scan2 <<<1, 128, 0, stream>>>(bsum, nb);
        k_scan3 <<<nb, 256, 0, stream>>>(rowptr, fill, bsum, N, E);
        k_scatter_direct<<<(E + B - 1) / B, B, 0, stream>>>(src, dst, fill, esrc, E);
    }

    k_gemm1 <<<(N + 63) / 64, 256, 0, stream>>>(x, W1, dinv, hb, N);
    k_agg1  <<<(N + 3) / 4, 256, 0, stream>>>(rowptr, esrc, hb, dinv, b1, o1b, N);
    k_gemm2m<<<(N + 63) / 64, 256, 0, stream>>>(o1b, W2, dinv, h2b, N);
    k_agg2  <<<(N + 63) / 64, 256, 0, stream>>>(rowptr, esrc, h2b, dinv, b2, out, N);
}

// Round 16
// 142.420 us; speedup vs baseline: 1.2811x; 1.1023x over previous
//
#include <hip/hip_runtime.h>

#define NFEAT 128
#define NHID  64
#define NOUT  21
#define BSH   7            // 128 nodes / bucket
#define BCAP  8192         // max edges LDS-sorted per bucket
#define CHUNK 4096         // edges per sort block (16 KB private region)
#define EPT   16           // edges per thread in k_lsort
#define PADI  16           // ints per padded counter (64 B)
#define NBUKMAX 1024       // nbuk ceiling for the packed path (N <= 2^17)

typedef unsigned int uint;
typedef unsigned short ushort_t;

typedef __bf16 bf16_t;
typedef bf16_t bf16x8 __attribute__((ext_vector_type(8)));
typedef float  f32x4  __attribute__((ext_vector_type(4)));

// bf16 pack/unpack (RTN-even)
__device__ inline uint packbf2(float a, float b) {
    uint ua = __float_as_uint(a), ub = __float_as_uint(b);
    ua = (ua + 0x7FFFu + ((ua >> 16) & 1u)) >> 16;
    ub = (ub + 0x7FFFu + ((ub >> 16) & 1u)) >> 16;
    return ua | (ub << 16);
}
__device__ inline float bflo(uint v) { return __uint_as_float(v << 16); }
__device__ inline float bfhi(uint v) { return __uint_as_float(v & 0xffff0000u); }

// ============ pass A: per-chunk LDS counting sort by bucket ============

__global__ __launch_bounds__(256) void k_lsort(const int* __restrict__ src, const int* __restrict__ dst,
                                               uint* __restrict__ ebuf, int* __restrict__ tab,
                                               int* __restrict__ gcnt, int E, int nbuk) {
    __shared__ int  lcnt[NBUKMAX + 1];
    __shared__ int  lsum[256];
    __shared__ uint lsorted[CHUNK];
    int c = blockIdx.x, tid = threadIdx.x;
    int base = c * CHUNK;
    int ccnt = min(CHUNK, E - base);

    for (int j = tid; j <= nbuk; j += 256) lcnt[j] = 0;
    __syncthreads();

    int  buk[EPT];
    uint rec[EPT];
#pragma unroll
    for (int g = 0; g < EPT / 4; ++g) {
        int e0 = base + g * 1024 + tid * 4;
        int4 dv, sv;
        if (e0 + 3 < E) {
            dv = *(const int4*)&dst[e0];
            sv = *(const int4*)&src[e0];
        } else {
            dv = make_int4(0, 0, 0, 0); sv = dv;
            if (e0     < E) { dv.x = dst[e0];     sv.x = src[e0]; }
            if (e0 + 1 < E) { dv.y = dst[e0 + 1]; sv.y = src[e0 + 1]; }
            if (e0 + 2 < E) { dv.z = dst[e0 + 2]; sv.z = src[e0 + 2]; }
        }
        int dd[4] = {dv.x, dv.y, dv.z, dv.w};
        int ss[4] = {sv.x, sv.y, sv.z, sv.w};
#pragma unroll
        for (int j = 0; j < 4; ++j) {
            int k = g * 4 + j;
            buk[k] = -1;
            if (e0 + j < E) {
                buk[k] = dd[j] >> BSH;
                rec[k] = ((uint)(dd[j] & ((1 << BSH) - 1)) << 17) | (uint)ss[j];
                atomicAdd(&lcnt[buk[k]], 1);
            }
        }
    }
    __syncthreads();

    int g = (nbuk + 255) / 256;
    int j0 = tid * g;
    int s = 0;
    for (int j = 0; j < g; ++j) { int idx = j0 + j; if (idx < nbuk) s += lcnt[idx]; }
    lsum[tid] = s;
    __syncthreads();
    for (int off = 1; off < 256; off <<= 1) {
        int t = (tid >= off) ? lsum[tid - off] : 0;
        __syncthreads();
        lsum[tid] += t;
        __syncthreads();
    }
    int run = lsum[tid] - s;
    for (int j = 0; j < g; ++j) {
        int idx = j0 + j;
        if (idx < nbuk) { int cv = lcnt[idx]; lcnt[idx] = run; run += cv; }
    }
    __syncthreads();
    if (tid == 0) lcnt[nbuk] = ccnt;
    __syncthreads();

    for (int j = tid; j < nbuk; j += 256) {
        int st = lcnt[j];
        tab[(size_t)c * (nbuk + 1) + j] = st;
        int cj = lcnt[j + 1] - st;
        if (cj) atomicAdd(&gcnt[j * PADI], cj);
    }
    if (tid == 0) tab[(size_t)c * (nbuk + 1) + nbuk] = ccnt;
    __syncthreads();

#pragma unroll
    for (int k = 0; k < EPT; ++k) {
        if (buk[k] >= 0) {
            int pos = atomicAdd(&lcnt[buk[k]], 1);
            lsorted[pos] = rec[k];
        }
    }
    __syncthreads();
    for (int i = tid * 4; i + 3 < ccnt; i += 1024)
        *(uint4*)&ebuf[base + i] = *(uint4*)&lsorted[i];
    int tail = ccnt & ~3;
    for (int i = tail + tid; i < ccnt; i += 256) ebuf[base + i] = lsorted[i];
}

// ============ pass B: single-ebuf-pass bucket sort (bscan fused) ============

__global__ __launch_bounds__(256) void k_bsort2(const uint* __restrict__ ebuf, const int* __restrict__ tab,
                                                const int* __restrict__ gcnt,
                                                int* __restrict__ rowptr, float* __restrict__ dinv,
                                                int* __restrict__ esrc, int nchunk, int nbuk, int N, int E) {
    __shared__ int  ncnt[128];
    __shared__ int  sc[128];
    __shared__ int  lcur[128];
    __shared__ int  rsum[256];
    __shared__ uint stash[BCAP];
    __shared__ int  lpos;
    int b = blockIdx.x, tid = threadIdx.x;
    int nb0 = b << BSH;
    int cnt_b = gcnt[b * PADI];
    bool fits = (cnt_b <= BCAP);

    int ps = 0;
    for (int j = tid; j < b; j += 256) ps += gcnt[j * PADI];
    rsum[tid] = ps;
    __syncthreads();
    for (int off = 128; off >= 1; off >>= 1) {
        if (tid < off) rsum[tid] += rsum[tid + off];
        __syncthreads();
    }
    int bb = rsum[0];

    if (tid < 128) ncnt[tid] = 0;
    if (tid == 0) {
        lpos = 0;
        if (b == nbuk - 1) rowptr[N] = E;
    }
    __syncthreads();

    for (int c = tid; c < nchunk; c += 256) {
        const int* trow = tab + (size_t)c * (nbuk + 1);
        int s0 = trow[b], e0 = trow[b + 1];
        int len = e0 - s0;
        if (len <= 0) continue;
        const uint* pb = ebuf + (size_t)c * CHUNK;
        if (fits) {
            int pos = atomicAdd(&lpos, len);
            for (int i = 0; i < len; ++i) {
                uint r = pb[s0 + i];
                stash[pos + i] = r;
                atomicAdd(&ncnt[r >> 17], 1);
            }
        } else {
            for (int i = 0; i < len; ++i) atomicAdd(&ncnt[pb[s0 + i] >> 17], 1);
        }
    }
    __syncthreads();

    int v = (tid < 128) ? ncnt[tid] : 0;
    if (tid < 128) sc[tid] = v;
    __syncthreads();
    for (int off = 1; off < 128; off <<= 1) {
        int t = (tid >= off && tid < 128) ? sc[tid - off] : 0;
        __syncthreads();
        if (tid < 128) sc[tid] += t;
        __syncthreads();
    }
    if (tid < 128) {
        int excl = sc[tid] - v;
        int node = nb0 + tid;
        if (node < N) {
            rowptr[node] = bb + excl;
            dinv[node] = rsqrtf((float)(v + 1));
        }
        lcur[tid] = bb + excl;
    }
    __syncthreads();

    if (fits) {
        for (int i = tid; i < cnt_b; i += 256) {
            uint r = stash[i];
            int pos = atomicAdd(&lcur[r >> 17], 1);
            esrc[pos] = (int)(r & 0x1FFFFu);
        }
    } else {
        for (int c = tid; c < nchunk; c += 256) {
            const int* trow = tab + (size_t)c * (nbuk + 1);
            int s0 = trow[b], e0 = trow[b + 1];
            const uint* pb = ebuf + (size_t)c * CHUNK;
            for (int i = s0; i < e0; ++i) {
                uint r = pb[i];
                int pos = atomicAdd(&lcur[r >> 17], 1);
                esrc[pos] = (int)(r & 0x1FFFFu);
            }
        }
    }
}

// ============ general-N fallback (N > 2^17) ============

__global__ __launch_bounds__(256) void k_count(const int* __restrict__ dst, int* cnt, int E) {
    int e = blockIdx.x * 256 + threadIdx.x;
    if (e < E) atomicAdd(&cnt[dst[e]], 1);
}

__global__ __launch_bounds__(256) void k_scan1(const int* __restrict__ cnt, int* __restrict__ rowptr,
                                               int* __restrict__ bsum, float* __restrict__ dinv, int N) {
    __shared__ int sh[256];
    int tid = threadIdx.x;
    int base = blockIdx.x * 1024 + tid * 4;
    int v[4]; int s = 0;
#pragma unroll
    for (int j = 0; j < 4; ++j) {
        v[j] = (base + j < N) ? cnt[base + j] : 0;
        if (base + j < N) dinv[base + j] = rsqrtf((float)(v[j] + 1));
        s += v[j];
    }
    sh[tid] = s; __syncthreads();
    for (int off = 1; off < 256; off <<= 1) {
        int t = (tid >= off) ? sh[tid - off] : 0;
        __syncthreads();
        sh[tid] += t;
        __syncthreads();
    }
    int run = sh[tid] - s;
#pragma unroll
    for (int j = 0; j < 4; ++j) { if (base + j < N) rowptr[base + j] = run; run += v[j]; }
    if (tid == 255) bsum[blockIdx.x] = sh[255];
}

__global__ __launch_bounds__(128) void k_scan2(int* bsum, int nb) {
    __shared__ int sh[128];
    int tid = threadIdx.x;
    int v = (tid < nb) ? bsum[tid] : 0;
    sh[tid] = v; __syncthreads();
    for (int off = 1; off < 128; off <<= 1) {
        int t = (tid >= off) ? sh[tid - off] : 0;
        __syncthreads();
        sh[tid] += t;
        __syncthreads();
    }
    if (tid < nb) bsum[tid] = sh[tid] - v;
}

__global__ __launch_bounds__(256) void k_scan3(int* __restrict__ rowptr, int* __restrict__ fill,
                                               const int* __restrict__ bsum, int N, int E) {
    int tid = threadIdx.x;
    int base = blockIdx.x * 1024 + tid * 4;
    int add = bsum[blockIdx.x];
#pragma unroll
    for (int j = 0; j < 4; ++j) {
        int idx = base + j;
        if (idx < N) {
            int r = rowptr[idx] + add;
            rowptr[idx] = r;
            fill[idx] = r;
        }
    }
    if (blockIdx.x == 0 && tid == 0) rowptr[N] = E;
}

__global__ __launch_bounds__(256) void k_scatter_direct(const int* __restrict__ src, const int* __restrict__ dst,
                                                        int* __restrict__ fill, int* __restrict__ esrc, int E) {
    int e = blockIdx.x * 256 + threadIdx.x;
    if (e >= E) return;
    int pos = atomicAdd(&fill[dst[e]], 1);
    esrc[pos] = src[e];
}

// ===== GEMM1 via MFMA: h' = dinv * (x @ W1) =====
// A-fragments loaded directly from global x into registers; W1^T in LDS.

__global__ __launch_bounds__(256) void k_gemm1(const float* __restrict__ x, const float* __restrict__ W1,
                                               const float* __restrict__ dinv, uint* __restrict__ hb, int N) {
    __shared__ ushort_t ws[64 * 136];   // W1^T bf16 [col][k], 17.4 KB
    int tid = threadIdx.x;
    int r0 = blockIdx.x * 64;

    {
        int col = tid & 63;
        int kb = (tid >> 6) * 32;
#pragma unroll
        for (int kk = 0; kk < 32; kk += 2) {
            float a = W1[(size_t)(kb + kk) * NHID + col];
            float b = W1[(size_t)(kb + kk + 1) * NHID + col];
            *(uint*)&ws[col * 136 + kb + kk] = packbf2(a, b);
        }
    }
    __syncthreads();

    int lane = tid & 63;
    int wrow = (tid >> 6) * 16;
    int lrow = lane & 15;
    int lk8  = (lane >> 4) * 8;

    int arow = r0 + wrow + lrow;
    bool aok = arow < N;
    const float* xr = x + (size_t)arow * NFEAT;

    f32x4 acc[4];
#pragma unroll
    for (int nt = 0; nt < 4; ++nt) acc[nt] = (f32x4){0.f, 0.f, 0.f, 0.f};

#pragma unroll
    for (int kq = 0; kq < 4; ++kq) {
        int kf = kq * 32 + lk8;
        float4 va = make_float4(0.f, 0.f, 0.f, 0.f), vb = va;
        if (aok) { va = *(const float4*)&xr[kf]; vb = *(const float4*)&xr[kf + 4]; }
        uint4 au = make_uint4(packbf2(va.x, va.y), packbf2(va.z, va.w),
                              packbf2(vb.x, vb.y), packbf2(vb.z, vb.w));
        bf16x8 a = *(bf16x8*)&au;
#pragma unroll
        for (int nt = 0; nt < 4; ++nt) {
            bf16x8 b = *(const bf16x8*)&ws[(nt * 16 + lrow) * 136 + kq * 32 + lk8];
            acc[nt] = __builtin_amdgcn_mfma_f32_16x16x32_bf16(a, b, acc[nt], 0, 0, 0);
        }
    }

    int orow0 = (lane >> 4) * 4;
    float dvv[4];
#pragma unroll
    for (int r = 0; r < 4; ++r) {
        int grow = r0 + wrow + orow0 + r;
        dvv[r] = (grow < N) ? dinv[grow] : 0.f;
    }
    ushort_t* hbs = (ushort_t*)hb;
#pragma unroll
    for (int nt = 0; nt < 4; ++nt) {
#pragma unroll
        for (int r = 0; r < 4; ++r) {
            int grow = r0 + wrow + orow0 + r;
            if (grow < N) {
                uint pb = packbf2(acc[nt][r] * dvv[r], 0.f);
                hbs[(size_t)grow * 64 + nt * 16 + lrow] = (ushort_t)(pb & 0xffffu);
            }
        }
    }
}

// ===== agg1: o1 = relu(b1 + dv*(h'[d] + sum_e h'[src_e])), packed bf16 out =====
// QUARTER-wave per node: 16 lanes x uint2 = full 128 B row; 4 nodes/wave.
// Per-node fixed overhead amortized 4x; 4 independent edge streams per wave.

__global__ __launch_bounds__(256) void k_agg1(const int* __restrict__ rowptr, const int* __restrict__ esrc,
                                              const uint* __restrict__ hb, const float* __restrict__ dinv,
                                              const float* __restrict__ b1, uint* __restrict__ o1b, int N) {
    int tid = threadIdx.x;
    int node = blockIdx.x * 16 + (tid >> 4);
    if (node >= N) return;
    int c = tid & 15;                         // owns feats 4c..4c+3 (one uint2)
    const uint2* hb2 = (const uint2*)hb;      // row = 16 uint2
    uint2 sv = hb2[(size_t)node * 16 + c];
    float a0 = bflo(sv.x), a1 = bfhi(sv.x), a2 = bflo(sv.y), a3 = bfhi(sv.y);
    int beg = rowptr[node], end = rowptr[node + 1];
    int i = beg;
    for (; i + 7 < end; i += 8) {
        int s0 = esrc[i],     s1 = esrc[i + 1], s2 = esrc[i + 2], s3 = esrc[i + 3];
        int s4 = esrc[i + 4], s5 = esrc[i + 5], s6 = esrc[i + 6], s7 = esrc[i + 7];
        uint2 v0 = hb2[(size_t)s0 * 16 + c];
        uint2 v1 = hb2[(size_t)s1 * 16 + c];
        uint2 v2 = hb2[(size_t)s2 * 16 + c];
        uint2 v3 = hb2[(size_t)s3 * 16 + c];
        uint2 v4 = hb2[(size_t)s4 * 16 + c];
        uint2 v5 = hb2[(size_t)s5 * 16 + c];
        uint2 v6 = hb2[(size_t)s6 * 16 + c];
        uint2 v7 = hb2[(size_t)s7 * 16 + c];
        a0 += bflo(v0.x) + bflo(v1.x); a1 += bfhi(v0.x) + bfhi(v1.x);
        a2 += bflo(v0.y) + bflo(v1.y); a3 += bfhi(v0.y) + bfhi(v1.y);
        a0 += bflo(v2.x) + bflo(v3.x); a1 += bfhi(v2.x) + bfhi(v3.x);
        a2 += bflo(v2.y) + bflo(v3.y); a3 += bfhi(v2.y) + bfhi(v3.y);
        a0 += bflo(v4.x) + bflo(v5.x); a1 += bfhi(v4.x) + bfhi(v5.x);
        a2 += bflo(v4.y) + bflo(v5.y); a3 += bfhi(v4.y) + bfhi(v5.y);
        a0 += bflo(v6.x) + bflo(v7.x); a1 += bfhi(v6.x) + bfhi(v7.x);
        a2 += bflo(v6.y) + bflo(v7.y); a3 += bfhi(v6.y) + bfhi(v7.y);
    }
    for (; i < end; ++i) {
        uint2 v = hb2[(size_t)esrc[i] * 16 + c];
        a0 += bflo(v.x); a1 += bfhi(v.x);
        a2 += bflo(v.y); a3 += bfhi(v.y);
    }
    float dv = dinv[node];
    float4 bv = *(const float4*)&b1[c * 4];
    float r0 = fmaxf(fmaf(a0, dv, bv.x), 0.f);
    float r1 = fmaxf(fmaf(a1, dv, bv.y), 0.f);
    float r2 = fmaxf(fmaf(a2, dv, bv.z), 0.f);
    float r3 = fmaxf(fmaf(a3, dv, bv.w), 0.f);
    ((uint2*)o1b)[(size_t)node * 16 + c] = make_uint2(packbf2(r0, r1), packbf2(r2, r3));
}

// ===== GEMM2 via MFMA: h2' = dinv * (o1 @ W2), cols padded to 32 =====

__global__ __launch_bounds__(256) void k_gemm2m(const uint* __restrict__ o1b, const float* __restrict__ W2,
                                                const float* __restrict__ dinv, uint* __restrict__ h2b, int N) {
    __shared__ ushort_t ws[32 * 136];   // 8.7 KB
    int tid = threadIdx.x;
    int r0 = blockIdx.x * 64;

    {
        int col = tid & 31;
        int kb = (tid >> 5) * 8;
#pragma unroll
        for (int kk = 0; kk < 8; kk += 2) {
            float a = (col < NOUT) ? W2[(size_t)(kb + kk) * NOUT + col] : 0.f;
            float b = (col < NOUT) ? W2[(size_t)(kb + kk + 1) * NOUT + col] : 0.f;
            *(uint*)&ws[col * 136 + kb + kk] = packbf2(a, b);
        }
    }
    __syncthreads();

    int lane = tid & 63;
    int wrow = (tid >> 6) * 16;
    int lrow = lane & 15;
    int lk8  = (lane >> 4) * 8;

    int arow = r0 + wrow + lrow;
    bool aok = arow < N;
    const ushort_t* orp = (const ushort_t*)o1b + (size_t)arow * 64;

    f32x4 acc[2];
#pragma unroll
    for (int nt = 0; nt < 2; ++nt) acc[nt] = (f32x4){0.f, 0.f, 0.f, 0.f};

#pragma unroll
    for (int kq = 0; kq < 2; ++kq) {
        uint4 au = make_uint4(0u, 0u, 0u, 0u);
        if (aok) au = *(const uint4*)&orp[kq * 32 + lk8];
        bf16x8 a = *(bf16x8*)&au;
#pragma unroll
        for (int nt = 0; nt < 2; ++nt) {
            bf16x8 b = *(const bf16x8*)&ws[(nt * 16 + lrow) * 136 + kq * 32 + lk8];
            acc[nt] = __builtin_amdgcn_mfma_f32_16x16x32_bf16(a, b, acc[nt], 0, 0, 0);
        }
    }

    int orow0 = (lane >> 4) * 4;
    float dvv[4];
#pragma unroll
    for (int r = 0; r < 4; ++r) {
        int grow = r0 + wrow + orow0 + r;
        dvv[r] = (grow < N) ? dinv[grow] : 0.f;
    }
    ushort_t* h2s = (ushort_t*)h2b;
#pragma unroll
    for (int nt = 0; nt < 2; ++nt) {
#pragma unroll
        for (int r = 0; r < 4; ++r) {
            int grow = r0 + wrow + orow0 + r;
            if (grow < N) {
                uint pb = packbf2(acc[nt][r] * dvv[r], 0.f);
                h2s[(size_t)grow * 32 + nt * 16 + lrow] = (ushort_t)(pb & 0xffffu);
            }
        }
    }
}

// ===== agg2: out[d] = b2 + dv_d*(h2'[d] + sum_e h2'[src_e]) =====

__global__ __launch_bounds__(256) void k_agg2(const int* __restrict__ rowptr, const int* __restrict__ esrc,
                                              const uint* __restrict__ h2b, const float* __restrict__ dinv,
                                              const float* __restrict__ b2, float* __restrict__ out, int N) {
    int tid = threadIdx.x;
    int node = blockIdx.x * 64 + (tid >> 2);
    if (node >= N) return;
    int q = tid & 3;
    uint4 sv = *((const uint4*)(h2b + (size_t)node * 16) + q);
    float a0 = bflo(sv.x), a1 = bfhi(sv.x), a2 = bflo(sv.y), a3 = bfhi(sv.y);
    float a4 = bflo(sv.z), a5 = bfhi(sv.z), a6 = bflo(sv.w), a7 = bfhi(sv.w);
    int beg = rowptr[node], end = rowptr[node + 1];
    int i = beg;
    for (; i + 3 < end; i += 4) {
        int s0 = esrc[i], s1 = esrc[i + 1], s2 = esrc[i + 2], s3 = esrc[i + 3];
        uint4 v0 = *((const uint4*)(h2b + (size_t)s0 * 16) + q);
        uint4 v1 = *((const uint4*)(h2b + (size_t)s1 * 16) + q);
        uint4 v2 = *((const uint4*)(h2b + (size_t)s2 * 16) + q);
        uint4 v3 = *((const uint4*)(h2b + (size_t)s3 * 16) + q);
        a0 += bflo(v0.x) + bflo(v1.x);
        a1 += bfhi(v0.x) + bfhi(v1.x);
        a2 += bflo(v0.y) + bflo(v1.y);
        a3 += bfhi(v0.y) + bfhi(v1.y);
        a4 += bflo(v0.z) + bflo(v1.z);
        a5 += bfhi(v0.z) + bfhi(v1.z);
        a6 += bflo(v0.w) + bflo(v1.w);
        a7 += bfhi(v0.w) + bfhi(v1.w);
        a0 += bflo(v2.x) + bflo(v3.x);
        a1 += bfhi(v2.x) + bfhi(v3.x);
        a2 += bflo(v2.y) + bflo(v3.y);
        a3 += bfhi(v2.y) + bfhi(v3.y);
        a4 += bflo(v2.z) + bflo(v3.z);
        a5 += bfhi(v2.z) + bfhi(v3.z);
        a6 += bflo(v2.w) + bflo(v3.w);
        a7 += bfhi(v2.w) + bfhi(v3.w);
    }
    for (; i < end; ++i) {
        uint4 v0 = *((const uint4*)(h2b + (size_t)esrc[i] * 16) + q);
        a0 += bflo(v0.x); a1 += bfhi(v0.x);
        a2 += bflo(v0.y); a3 += bfhi(v0.y);
        a4 += bflo(v0.z); a5 += bfhi(v0.z);
        a6 += bflo(v0.w); a7 += bfhi(v0.w);
    }
    float dv = dinv[node];
    float* orow = out + (size_t)node * NOUT;
    int col = q * 8;
    float av[8] = {a0, a1, a2, a3, a4, a5, a6, a7};
#pragma unroll
    for (int j = 0; j < 8; ++j)
        if (col + j < NOUT) orow[col + j] = fmaf(dv, av[j], b2[col + j]);
}

// ================= launch =================

extern "C" void kernel_launch(void* const* d_in, const int* in_sizes, int n_in,
                              void* d_out, int out_size, void* d_ws, size_t ws_size,
                              hipStream_t stream) {
    const float* x  = (const float*)d_in[0];
    const int*   ei = (const int*)d_in[1];
    const float* W1 = (const float*)d_in[2];
    const float* b1 = (const float*)d_in[3];
    const float* W2 = (const float*)d_in[4];
    const float* b2 = (const float*)d_in[5];
    float* out = (float*)d_out;

    int N = in_sizes[0] / NFEAT;
    int E = in_sizes[1] / 2;
    const int* src = ei;
    const int* dst = ei + E;
    int NBUK = (N + (1 << BSH) - 1) >> BSH;
    int NCHUNK = (E + CHUNK - 1) / CHUNK;

    char* p = (char*)d_ws;
    auto alloc = [&](size_t bytes) { void* r = (void*)p; p += (bytes + 255) & ~(size_t)255; return r; };
    int*   rowptr = (int*)alloc((size_t)(N + 1) * 4);
    int*   gcnt   = (int*)alloc((size_t)NBUK * PADI * 4);
    int*   tab    = (int*)alloc((size_t)NCHUNK * (NBUK + 1) * 4);
    uint*  ebuf   = (uint*)alloc((size_t)E * 4);
    int*   esrc   = (int*)alloc((size_t)E * 4);
    float* dinv   = (float*)alloc((size_t)N * 4);
    uint*  hb     = (uint*)alloc((size_t)N * 32 * 4);   // h'  bf16 [N][64]
    uint*  o1b    = (uint*)alloc((size_t)N * 32 * 4);   // o1  bf16 [N][64]
    uint*  h2b    = (uint*)alloc((size_t)N * 16 * 4);   // h2' bf16 [N][32] (padded)
    int*   cnt    = (int*)alloc((size_t)N * 4);      // fallback only
    int*   fill   = (int*)alloc((size_t)N * 4);      // fallback only
    int*   bsum   = (int*)alloc(128 * 4);            // fallback only

    const int B = 256;

    if (N <= (1 << 17)) {
        hipMemsetAsync(gcnt, 0, (size_t)NBUK * PADI * 4, stream);
        k_lsort <<<NCHUNK, 256, 0, stream>>>(src, dst, ebuf, tab, gcnt, E, NBUK);
        k_bsort2<<<NBUK, 256, 0, stream>>>(ebuf, tab, gcnt, rowptr, dinv, esrc, NCHUNK, NBUK, N, E);
    } else {
        int nb = (N + 1023) / 1024;
        hipMemsetAsync(cnt, 0, (size_t)N * 4, stream);
        k_count <<<(E + B - 1) / B, B, 0, stream>>>(dst, cnt, E);
        k_scan1 <<<nb, 256, 0, stream>>>(cnt, rowptr, bsum, dinv, N);
        k_scan2 <<<1, 128, 0, stream>>>(bsum, nb);
        k_scan3 <<<nb, 256, 0, stream>>>(rowptr, fill, bsum, N, E);
        k_scatter_direct<<<(E + B - 1) / B, B, 0, stream>>>(src, dst, fill, esrc, E);
    }

    k_gemm1 <<<(N + 63) / 64, 256, 0, stream>>>(x, W1, dinv, hb, N);
    k_agg1  <<<(N + 15) / 16, 256, 0, stream>>>(rowptr, esrc, hb, dinv, b1, o1b, N);
    k_gemm2m<<<(N + 63) / 64, 256, 0, stream>>>(o1b, W2, dinv, h2b, N);
    k_agg2  <<<(N + 63) / 64, 256, 0, stream>>>(rowptr, esrc, h2b, dinv, b2, out, N);
}

// Round 17
// 142.262 us; speedup vs baseline: 1.2825x; 1.0011x over previous
//
#include <hip/hip_runtime.h>

#define NFEAT 128
#define NHID  64
#define NOUT  21
#define BSH   7            // 128 nodes / bucket
#define BCAP  8192         // max edges LDS-sorted per bucket
#define CHUNK 4096         // edges per sort block (16 KB private region)
#define EPT   16           // edges per thread in k_lsort
#define PADI  16           // ints per padded counter (64 B)
#define NBUKMAX 1024       // nbuk ceiling for the packed path (N <= 2^17)

typedef unsigned int uint;
typedef unsigned short ushort_t;

typedef __bf16 bf16_t;
typedef bf16_t bf16x8 __attribute__((ext_vector_type(8)));
typedef float  f32x4  __attribute__((ext_vector_type(4)));

// bf16 pack/unpack (RTN-even)
__device__ inline uint packbf2(float a, float b) {
    uint ua = __float_as_uint(a), ub = __float_as_uint(b);
    ua = (ua + 0x7FFFu + ((ua >> 16) & 1u)) >> 16;
    ub = (ub + 0x7FFFu + ((ub >> 16) & 1u)) >> 16;
    return ua | (ub << 16);
}
__device__ inline float bflo(uint v) { return __uint_as_float(v << 16); }
__device__ inline float bfhi(uint v) { return __uint_as_float(v & 0xffff0000u); }

// ============ zero scratch (replaces pathological runtime fill kernel) ============

__global__ __launch_bounds__(256) void k_zero(uint* __restrict__ p, int n4) {
    int i = blockIdx.x * 256 + threadIdx.x;
    if (i < n4) ((uint4*)p)[i] = make_uint4(0u, 0u, 0u, 0u);
}

// ============ pass A: per-chunk LDS counting sort by bucket ============

__global__ __launch_bounds__(256) void k_lsort(const int* __restrict__ src, const int* __restrict__ dst,
                                               uint* __restrict__ ebuf, int* __restrict__ tab,
                                               int* __restrict__ gcnt, int E, int nbuk) {
    __shared__ int  lcnt[NBUKMAX + 1];
    __shared__ int  lsum[256];
    __shared__ uint lsorted[CHUNK];
    int c = blockIdx.x, tid = threadIdx.x;
    int base = c * CHUNK;
    int ccnt = min(CHUNK, E - base);

    for (int j = tid; j <= nbuk; j += 256) lcnt[j] = 0;
    __syncthreads();

    int  buk[EPT];
    uint rec[EPT];
#pragma unroll
    for (int g = 0; g < EPT / 4; ++g) {
        int e0 = base + g * 1024 + tid * 4;
        int4 dv, sv;
        if (e0 + 3 < E) {
            dv = *(const int4*)&dst[e0];
            sv = *(const int4*)&src[e0];
        } else {
            dv = make_int4(0, 0, 0, 0); sv = dv;
            if (e0     < E) { dv.x = dst[e0];     sv.x = src[e0]; }
            if (e0 + 1 < E) { dv.y = dst[e0 + 1]; sv.y = src[e0 + 1]; }
            if (e0 + 2 < E) { dv.z = dst[e0 + 2]; sv.z = src[e0 + 2]; }
        }
        int dd[4] = {dv.x, dv.y, dv.z, dv.w};
        int ss[4] = {sv.x, sv.y, sv.z, sv.w};
#pragma unroll
        for (int j = 0; j < 4; ++j) {
            int k = g * 4 + j;
            buk[k] = -1;
            if (e0 + j < E) {
                buk[k] = dd[j] >> BSH;
                rec[k] = ((uint)(dd[j] & ((1 << BSH) - 1)) << 17) | (uint)ss[j];
                atomicAdd(&lcnt[buk[k]], 1);
            }
        }
    }
    __syncthreads();

    int g = (nbuk + 255) / 256;
    int j0 = tid * g;
    int s = 0;
    for (int j = 0; j < g; ++j) { int idx = j0 + j; if (idx < nbuk) s += lcnt[idx]; }
    lsum[tid] = s;
    __syncthreads();
    for (int off = 1; off < 256; off <<= 1) {
        int t = (tid >= off) ? lsum[tid - off] : 0;
        __syncthreads();
        lsum[tid] += t;
        __syncthreads();
    }
    int run = lsum[tid] - s;
    for (int j = 0; j < g; ++j) {
        int idx = j0 + j;
        if (idx < nbuk) { int cv = lcnt[idx]; lcnt[idx] = run; run += cv; }
    }
    __syncthreads();
    if (tid == 0) lcnt[nbuk] = ccnt;
    __syncthreads();

    for (int j = tid; j < nbuk; j += 256) {
        int st = lcnt[j];
        tab[(size_t)c * (nbuk + 1) + j] = st;
        int cj = lcnt[j + 1] - st;
        if (cj) atomicAdd(&gcnt[j * PADI], cj);
    }
    if (tid == 0) tab[(size_t)c * (nbuk + 1) + nbuk] = ccnt;
    __syncthreads();

#pragma unroll
    for (int k = 0; k < EPT; ++k) {
        if (buk[k] >= 0) {
            int pos = atomicAdd(&lcnt[buk[k]], 1);
            lsorted[pos] = rec[k];
        }
    }
    __syncthreads();
    for (int i = tid * 4; i + 3 < ccnt; i += 1024)
        *(uint4*)&ebuf[base + i] = *(uint4*)&lsorted[i];
    int tail = ccnt & ~3;
    for (int i = tail + tid; i < ccnt; i += 256) ebuf[base + i] = lsorted[i];
}

// ============ pass B: single-ebuf-pass bucket sort (bscan fused) ============

__global__ __launch_bounds__(256) void k_bsort2(const uint* __restrict__ ebuf, const int* __restrict__ tab,
                                                const int* __restrict__ gcnt,
                                                int* __restrict__ rowptr, float* __restrict__ dinv,
                                                int* __restrict__ esrc, int nchunk, int nbuk, int N, int E) {
    __shared__ int  ncnt[128];
    __shared__ int  sc[128];
    __shared__ int  lcur[128];
    __shared__ int  rsum[256];
    __shared__ uint stash[BCAP];
    __shared__ int  lpos;
    int b = blockIdx.x, tid = threadIdx.x;
    int nb0 = b << BSH;
    int cnt_b = gcnt[b * PADI];
    bool fits = (cnt_b <= BCAP);

    int ps = 0;
    for (int j = tid; j < b; j += 256) ps += gcnt[j * PADI];
    rsum[tid] = ps;
    __syncthreads();
    for (int off = 128; off >= 1; off >>= 1) {
        if (tid < off) rsum[tid] += rsum[tid + off];
        __syncthreads();
    }
    int bb = rsum[0];

    if (tid < 128) ncnt[tid] = 0;
    if (tid == 0) {
        lpos = 0;
        if (b == nbuk - 1) rowptr[N] = E;
    }
    __syncthreads();

    for (int c = tid; c < nchunk; c += 256) {
        const int* trow = tab + (size_t)c * (nbuk + 1);
        int s0 = trow[b], e0 = trow[b + 1];
        int len = e0 - s0;
        if (len <= 0) continue;
        const uint* pb = ebuf + (size_t)c * CHUNK;
        if (fits) {
            int pos = atomicAdd(&lpos, len);
            for (int i = 0; i < len; ++i) {
                uint r = pb[s0 + i];
                stash[pos + i] = r;
                atomicAdd(&ncnt[r >> 17], 1);
            }
        } else {
            for (int i = 0; i < len; ++i) atomicAdd(&ncnt[pb[s0 + i] >> 17], 1);
        }
    }
    __syncthreads();

    int v = (tid < 128) ? ncnt[tid] : 0;
    if (tid < 128) sc[tid] = v;
    __syncthreads();
    for (int off = 1; off < 128; off <<= 1) {
        int t = (tid >= off && tid < 128) ? sc[tid - off] : 0;
        __syncthreads();
        if (tid < 128) sc[tid] += t;
        __syncthreads();
    }
    if (tid < 128) {
        int excl = sc[tid] - v;
        int node = nb0 + tid;
        if (node < N) {
            rowptr[node] = bb + excl;
            dinv[node] = rsqrtf((float)(v + 1));
        }
        lcur[tid] = bb + excl;
    }
    __syncthreads();

    if (fits) {
        for (int i = tid; i < cnt_b; i += 256) {
            uint r = stash[i];
            int pos = atomicAdd(&lcur[r >> 17], 1);
            esrc[pos] = (int)(r & 0x1FFFFu);
        }
    } else {
        for (int c = tid; c < nchunk; c += 256) {
            const int* trow = tab + (size_t)c * (nbuk + 1);
            int s0 = trow[b], e0 = trow[b + 1];
            const uint* pb = ebuf + (size_t)c * CHUNK;
            for (int i = s0; i < e0; ++i) {
                uint r = pb[i];
                int pos = atomicAdd(&lcur[r >> 17], 1);
                esrc[pos] = (int)(r & 0x1FFFFu);
            }
        }
    }
}

// ============ general-N fallback (N > 2^17) ============

__global__ __launch_bounds__(256) void k_count(const int* __restrict__ dst, int* cnt, int E) {
    int e = blockIdx.x * 256 + threadIdx.x;
    if (e < E) atomicAdd(&cnt[dst[e]], 1);
}

__global__ __launch_bounds__(256) void k_scan1(const int* __restrict__ cnt, int* __restrict__ rowptr,
                                               int* __restrict__ bsum, float* __restrict__ dinv, int N) {
    __shared__ int sh[256];
    int tid = threadIdx.x;
    int base = blockIdx.x * 1024 + tid * 4;
    int v[4]; int s = 0;
#pragma unroll
    for (int j = 0; j < 4; ++j) {
        v[j] = (base + j < N) ? cnt[base + j] : 0;
        if (base + j < N) dinv[base + j] = rsqrtf((float)(v[j] + 1));
        s += v[j];
    }
    sh[tid] = s; __syncthreads();
    for (int off = 1; off < 256; off <<= 1) {
        int t = (tid >= off) ? sh[tid - off] : 0;
        __syncthreads();
        sh[tid] += t;
        __syncthreads();
    }
    int run = sh[tid] - s;
#pragma unroll
    for (int j = 0; j < 4; ++j) { if (base + j < N) rowptr[base + j] = run; run += v[j]; }
    if (tid == 255) bsum[blockIdx.x] = sh[255];
}

__global__ __launch_bounds__(128) void k_scan2(int* bsum, int nb) {
    __shared__ int sh[128];
    int tid = threadIdx.x;
    int v = (tid < nb) ? bsum[tid] : 0;
    sh[tid] = v; __syncthreads();
    for (int off = 1; off < 128; off <<= 1) {
        int t = (tid >= off) ? sh[tid - off] : 0;
        __syncthreads();
        sh[tid] += t;
        __syncthreads();
    }
    if (tid < nb) bsum[tid] = sh[tid] - v;
}

__global__ __launch_bounds__(256) void k_scan3(int* __restrict__ rowptr, int* __restrict__ fill,
                                               const int* __restrict__ bsum, int N, int E) {
    int tid = threadIdx.x;
    int base = blockIdx.x * 1024 + tid * 4;
    int add = bsum[blockIdx.x];
#pragma unroll
    for (int j = 0; j < 4; ++j) {
        int idx = base + j;
        if (idx < N) {
            int r = rowptr[idx] + add;
            rowptr[idx] = r;
            fill[idx] = r;
        }
    }
    if (blockIdx.x == 0 && tid == 0) rowptr[N] = E;
}

__global__ __launch_bounds__(256) void k_scatter_direct(const int* __restrict__ src, const int* __restrict__ dst,
                                                        int* __restrict__ fill, int* __restrict__ esrc, int E) {
    int e = blockIdx.x * 256 + threadIdx.x;
    if (e >= E) return;
    int pos = atomicAdd(&fill[dst[e]], 1);
    esrc[pos] = src[e];
}

// ===== GEMM1 via MFMA: h' = dinv * (x @ W1) =====
// A-fragments loaded directly from global x into registers; W1^T in LDS.

__global__ __launch_bounds__(256) void k_gemm1(const float* __restrict__ x, const float* __restrict__ W1,
                                               const float* __restrict__ dinv, uint* __restrict__ hb, int N) {
    __shared__ ushort_t ws[64 * 136];   // W1^T bf16 [col][k], 17.4 KB
    int tid = threadIdx.x;
    int r0 = blockIdx.x * 64;

    {
        int col = tid & 63;
        int kb = (tid >> 6) * 32;
#pragma unroll
        for (int kk = 0; kk < 32; kk += 2) {
            float a = W1[(size_t)(kb + kk) * NHID + col];
            float b = W1[(size_t)(kb + kk + 1) * NHID + col];
            *(uint*)&ws[col * 136 + kb + kk] = packbf2(a, b);
        }
    }
    __syncthreads();

    int lane = tid & 63;
    int wrow = (tid >> 6) * 16;
    int lrow = lane & 15;
    int lk8  = (lane >> 4) * 8;

    int arow = r0 + wrow + lrow;
    bool aok = arow < N;
    const float* xr = x + (size_t)arow * NFEAT;

    f32x4 acc[4];
#pragma unroll
    for (int nt = 0; nt < 4; ++nt) acc[nt] = (f32x4){0.f, 0.f, 0.f, 0.f};

#pragma unroll
    for (int kq = 0; kq < 4; ++kq) {
        int kf = kq * 32 + lk8;
        float4 va = make_float4(0.f, 0.f, 0.f, 0.f), vb = va;
        if (aok) { va = *(const float4*)&xr[kf]; vb = *(const float4*)&xr[kf + 4]; }
        uint4 au = make_uint4(packbf2(va.x, va.y), packbf2(va.z, va.w),
                              packbf2(vb.x, vb.y), packbf2(vb.z, vb.w));
        bf16x8 a = *(bf16x8*)&au;
#pragma unroll
        for (int nt = 0; nt < 4; ++nt) {
            bf16x8 b = *(const bf16x8*)&ws[(nt * 16 + lrow) * 136 + kq * 32 + lk8];
            acc[nt] = __builtin_amdgcn_mfma_f32_16x16x32_bf16(a, b, acc[nt], 0, 0, 0);
        }
    }

    int orow0 = (lane >> 4) * 4;
    float dvv[4];
#pragma unroll
    for (int r = 0; r < 4; ++r) {
        int grow = r0 + wrow + orow0 + r;
        dvv[r] = (grow < N) ? dinv[grow] : 0.f;
    }
    ushort_t* hbs = (ushort_t*)hb;
#pragma unroll
    for (int nt = 0; nt < 4; ++nt) {
#pragma unroll
        for (int r = 0; r < 4; ++r) {
            int grow = r0 + wrow + orow0 + r;
            if (grow < N) {
                uint pb = packbf2(acc[nt][r] * dvv[r], 0.f);
                hbs[(size_t)grow * 64 + nt * 16 + lrow] = (ushort_t)(pb & 0xffffu);
            }
        }
    }
}

// ===== agg1: o1 = relu(b1 + dv*(h'[d] + sum_e h'[src_e])), packed bf16 out =====
// Quarter-wave per node: 16 lanes x uint2 = full 128 B row; 4 nodes/wave.

__global__ __launch_bounds__(256) void k_agg1(const int* __restrict__ rowptr, const int* __restrict__ esrc,
                                              const uint* __restrict__ hb, const float* __restrict__ dinv,
                                              const float* __restrict__ b1, uint* __restrict__ o1b, int N) {
    int tid = threadIdx.x;
    int node = blockIdx.x * 16 + (tid >> 4);
    if (node >= N) return;
    int c = tid & 15;
    const uint2* hb2 = (const uint2*)hb;
    uint2 sv = hb2[(size_t)node * 16 + c];
    float a0 = bflo(sv.x), a1 = bfhi(sv.x), a2 = bflo(sv.y), a3 = bfhi(sv.y);
    int beg = rowptr[node], end = rowptr[node + 1];
    int i = beg;
    for (; i + 7 < end; i += 8) {
        int s0 = esrc[i],     s1 = esrc[i + 1], s2 = esrc[i + 2], s3 = esrc[i + 3];
        int s4 = esrc[i + 4], s5 = esrc[i + 5], s6 = esrc[i + 6], s7 = esrc[i + 7];
        uint2 v0 = hb2[(size_t)s0 * 16 + c];
        uint2 v1 = hb2[(size_t)s1 * 16 + c];
        uint2 v2 = hb2[(size_t)s2 * 16 + c];
        uint2 v3 = hb2[(size_t)s3 * 16 + c];
        uint2 v4 = hb2[(size_t)s4 * 16 + c];
        uint2 v5 = hb2[(size_t)s5 * 16 + c];
        uint2 v6 = hb2[(size_t)s6 * 16 + c];
        uint2 v7 = hb2[(size_t)s7 * 16 + c];
        a0 += bflo(v0.x) + bflo(v1.x); a1 += bfhi(v0.x) + bfhi(v1.x);
        a2 += bflo(v0.y) + bflo(v1.y); a3 += bfhi(v0.y) + bfhi(v1.y);
        a0 += bflo(v2.x) + bflo(v3.x); a1 += bfhi(v2.x) + bfhi(v3.x);
        a2 += bflo(v2.y) + bflo(v3.y); a3 += bfhi(v2.y) + bfhi(v3.y);
        a0 += bflo(v4.x) + bflo(v5.x); a1 += bfhi(v4.x) + bfhi(v5.x);
        a2 += bflo(v4.y) + bflo(v5.y); a3 += bfhi(v4.y) + bfhi(v5.y);
        a0 += bflo(v6.x) + bflo(v7.x); a1 += bfhi(v6.x) + bfhi(v7.x);
        a2 += bflo(v6.y) + bflo(v7.y); a3 += bfhi(v6.y) + bfhi(v7.y);
    }
    for (; i < end; ++i) {
        uint2 v = hb2[(size_t)esrc[i] * 16 + c];
        a0 += bflo(v.x); a1 += bfhi(v.x);
        a2 += bflo(v.y); a3 += bfhi(v.y);
    }
    float dv = dinv[node];
    float4 bv = *(const float4*)&b1[c * 4];
    float r0 = fmaxf(fmaf(a0, dv, bv.x), 0.f);
    float r1 = fmaxf(fmaf(a1, dv, bv.y), 0.f);
    float r2 = fmaxf(fmaf(a2, dv, bv.z), 0.f);
    float r3 = fmaxf(fmaf(a3, dv, bv.w), 0.f);
    ((uint2*)o1b)[(size_t)node * 16 + c] = make_uint2(packbf2(r0, r1), packbf2(r2, r3));
}

// ===== GEMM2 via MFMA: h2' = dinv * (o1 @ W2), cols padded to 32 =====

__global__ __launch_bounds__(256) void k_gemm2m(const uint* __restrict__ o1b, const float* __restrict__ W2,
                                                const float* __restrict__ dinv, uint* __restrict__ h2b, int N) {
    __shared__ ushort_t ws[32 * 136];   // 8.7 KB
    int tid = threadIdx.x;
    int r0 = blockIdx.x * 64;

    {
        int col = tid & 31;
        int kb = (tid >> 5) * 8;
#pragma unroll
        for (int kk = 0; kk < 8; kk += 2) {
            float a = (col < NOUT) ? W2[(size_t)(kb + kk) * NOUT + col] : 0.f;
            float b = (col < NOUT) ? W2[(size_t)(kb + kk + 1) * NOUT + col] : 0.f;
            *(uint*)&ws[col * 136 + kb + kk] = packbf2(a, b);
        }
    }
    __syncthreads();

    int lane = tid & 63;
    int wrow = (tid >> 6) * 16;
    int lrow = lane & 15;
    int lk8  = (lane >> 4) * 8;

    int arow = r0 + wrow + lrow;
    bool aok = arow < N;
    const ushort_t* orp = (const ushort_t*)o1b + (size_t)arow * 64;

    f32x4 acc[2];
#pragma unroll
    for (int nt = 0; nt < 2; ++nt) acc[nt] = (f32x4){0.f, 0.f, 0.f, 0.f};

#pragma unroll
    for (int kq = 0; kq < 2; ++kq) {
        uint4 au = make_uint4(0u, 0u, 0u, 0u);
        if (aok) au = *(const uint4*)&orp[kq * 32 + lk8];
        bf16x8 a = *(bf16x8*)&au;
#pragma unroll
        for (int nt = 0; nt < 2; ++nt) {
            bf16x8 b = *(const bf16x8*)&ws[(nt * 16 + lrow) * 136 + kq * 32 + lk8];
            acc[nt] = __builtin_amdgcn_mfma_f32_16x16x32_bf16(a, b, acc[nt], 0, 0, 0);
        }
    }

    int orow0 = (lane >> 4) * 4;
    float dvv[4];
#pragma unroll
    for (int r = 0; r < 4; ++r) {
        int grow = r0 + wrow + orow0 + r;
        dvv[r] = (grow < N) ? dinv[grow] : 0.f;
    }
    ushort_t* h2s = (ushort_t*)h2b;
#pragma unroll
    for (int nt = 0; nt < 2; ++nt) {
#pragma unroll
        for (int r = 0; r < 4; ++r) {
            int grow = r0 + wrow + orow0 + r;
            if (grow < N) {
                uint pb = packbf2(acc[nt][r] * dvv[r], 0.f);
                h2s[(size_t)grow * 32 + nt * 16 + lrow] = (ushort_t)(pb & 0xffffu);
            }
        }
    }
}

// ===== agg2: out[d] = b2 + dv_d*(h2'[d] + sum_e h2'[src_e]) =====

__global__ __launch_bounds__(256) void k_agg2(const int* __restrict__ rowptr, const int* __restrict__ esrc,
                                              const uint* __restrict__ h2b, const float* __restrict__ dinv,
                                              const float* __restrict__ b2, float* __restrict__ out, int N) {
    int tid = threadIdx.x;
    int node = blockIdx.x * 64 + (tid >> 2);
    if (node >= N) return;
    int q = tid & 3;
    uint4 sv = *((const uint4*)(h2b + (size_t)node * 16) + q);
    float a0 = bflo(sv.x), a1 = bfhi(sv.x), a2 = bflo(sv.y), a3 = bfhi(sv.y);
    float a4 = bflo(sv.z), a5 = bfhi(sv.z), a6 = bflo(sv.w), a7 = bfhi(sv.w);
    int beg = rowptr[node], end = rowptr[node + 1];
    int i = beg;
    for (; i + 3 < end; i += 4) {
        int s0 = esrc[i], s1 = esrc[i + 1], s2 = esrc[i + 2], s3 = esrc[i + 3];
        uint4 v0 = *((const uint4*)(h2b + (size_t)s0 * 16) + q);
        uint4 v1 = *((const uint4*)(h2b + (size_t)s1 * 16) + q);
        uint4 v2 = *((const uint4*)(h2b + (size_t)s2 * 16) + q);
        uint4 v3 = *((const uint4*)(h2b + (size_t)s3 * 16) + q);
        a0 += bflo(v0.x) + bflo(v1.x);
        a1 += bfhi(v0.x) + bfhi(v1.x);
        a2 += bflo(v0.y) + bflo(v1.y);
        a3 += bfhi(v0.y) + bfhi(v1.y);
        a4 += bflo(v0.z) + bflo(v1.z);
        a5 += bfhi(v0.z) + bfhi(v1.z);
        a6 += bflo(v0.w) + bflo(v1.w);
        a7 += bfhi(v0.w) + bfhi(v1.w);
        a0 += bflo(v2.x) + bflo(v3.x);
        a1 += bfhi(v2.x) + bfhi(v3.x);
        a2 += bflo(v2.y) + bflo(v3.y);
        a3 += bfhi(v2.y) + bfhi(v3.y);
        a4 += bflo(v2.z) + bflo(v3.z);
        a5 += bfhi(v2.z) + bfhi(v3.z);
        a6 += bflo(v2.w) + bflo(v3.w);
        a7 += bfhi(v2.w) + bfhi(v3.w);
    }
    for (; i < end; ++i) {
        uint4 v0 = *((const uint4*)(h2b + (size_t)esrc[i] * 16) + q);
        a0 += bflo(v0.x); a1 += bfhi(v0.x);
        a2 += bflo(v0.y); a3 += bfhi(v0.y);
        a4 += bflo(v0.z); a5 += bfhi(v0.z);
        a6 += bflo(v0.w); a7 += bfhi(v0.w);
    }
    float dv = dinv[node];
    float* orow = out + (size_t)node * NOUT;
    int col = q * 8;
    float av[8] = {a0, a1, a2, a3, a4, a5, a6, a7};
#pragma unroll
    for (int j = 0; j < 8; ++j)
        if (col + j < NOUT) orow[col + j] = fmaf(dv, av[j], b2[col + j]);
}

// ================= launch =================

extern "C" void kernel_launch(void* const* d_in, const int* in_sizes, int n_in,
                              void* d_out, int out_size, void* d_ws, size_t ws_size,
                              hipStream_t stream) {
    const float* x  = (const float*)d_in[0];
    const int*   ei = (const int*)d_in[1];
    const float* W1 = (const float*)d_in[2];
    const float* b1 = (const float*)d_in[3];
    const float* W2 = (const float*)d_in[4];
    const float* b2 = (const float*)d_in[5];
    float* out = (float*)d_out;

    int N = in_sizes[0] / NFEAT;
    int E = in_sizes[1] / 2;
    const int* src = ei;
    const int* dst = ei + E;
    int NBUK = (N + (1 << BSH) - 1) >> BSH;
    int NCHUNK = (E + CHUNK - 1) / CHUNK;

    char* p = (char*)d_ws;
    auto alloc = [&](size_t bytes) { void* r = (void*)p; p += (bytes + 255) & ~(size_t)255; return r; };
    int*   rowptr = (int*)alloc((size_t)(N + 1) * 4);
    int*   gcnt   = (int*)alloc((size_t)NBUK * PADI * 4);
    int*   tab    = (int*)alloc((size_t)NCHUNK * (NBUK + 1) * 4);
    uint*  ebuf   = (uint*)alloc((size_t)E * 4);
    int*   esrc   = (int*)alloc((size_t)E * 4);
    float* dinv   = (float*)alloc((size_t)N * 4);
    uint*  hb     = (uint*)alloc((size_t)N * 32 * 4);   // h'  bf16 [N][64]
    uint*  o1b    = (uint*)alloc((size_t)N * 32 * 4);   // o1  bf16 [N][64]
    uint*  h2b    = (uint*)alloc((size_t)N * 16 * 4);   // h2' bf16 [N][32] (padded)
    int*   cnt    = (int*)alloc((size_t)N * 4);      // fallback only
    int*   fill   = (int*)alloc((size_t)N * 4);      // fallback only
    int*   bsum   = (int*)alloc(128 * 4);            // fallback only

    const int B = 256;

    if (N <= (1 << 17)) {
        int zn4 = (NBUK * PADI) / 4;                       // gcnt is PADI-aligned
        k_zero  <<<(zn4 + B - 1) / B, B, 0, stream>>>((uint*)gcnt, zn4);
        k_lsort <<<NCHUNK, 256, 0, stream>>>(src, dst, ebuf, tab, gcnt, E, NBUK);
        k_bsort2<<<NBUK, 256, 0, stream>>>(ebuf, tab, gcnt, rowptr, dinv, esrc, NCHUNK, NBUK, N, E);
    } else {
        int nb = (N + 1023) / 1024;
        int zn4 = (int)(((size_t)N * 4 + 15) / 16);
        k_zero  <<<(zn4 + B - 1) / B, B, 0, stream>>>((uint*)cnt, zn4);
        k_count <<<(E + B - 1) / B, B, 0, stream>>>(dst, cnt, E);
        k_scan1 <<<nb, 256, 0, stream>>>(cnt, rowptr, bsum, dinv, N);
        k_scan2 <<<1, 128, 0, stream>>>(bsum, nb);
        k_scan3 <<<nb, 256, 0, stream>>>(rowptr, fill, bsum, N, E);
        k_scatter_direct<<<(E + B - 1) / B, B, 0, stream>>>(src, dst, fill, esrc, E);
    }

    k_gemm1 <<<(N + 63) / 64, 256, 0, stream>>>(x, W1, dinv, hb, N);
    k_agg1  <<<(N + 15) / 16, 256, 0, stream>>>(rowptr, esrc, hb, dinv, b1, o1b, N);
    k_gemm2m<<<(N + 63) / 64, 256, 0, stream>>>(o1b, W2, dinv, h2b, N);
    k_agg2  <<<(N + 63) / 64, 256, 0, stream>>>(rowptr, esrc, h2b, dinv, b2, out, N);
}